// Round 1
// baseline (651.156 us; speedup 1.0000x reference)
//
#include <hip/hip_runtime.h>
#include <hip/hip_fp16.h>
#include <stdint.h>

// VGAE GCN encoder. CSR build via LDS-binned 2-phase bucket partition:
//   k_part: edges -> 782 buckets (128 dst-nodes each); per-block LDS rings of 40
//     slots/bucket, flushed in full 64B groups of 16 -> ~1x write amplification
//     (R4 showed 16x amp: 4B frontier writes from 8 non-coherent XCD L2s).
//   k_bscan: 782-entry exclusive scan -> bucket bases; offs[N]=E.
//   k_p2: per bucket: LDS degree count (emits offs+dinv), LDS rank, coalesced csr.
// k_gemm1 (standalone; R4's fusion made 12.5K partition blocks hog gemm's LDS):
//   h1 = x@W1 fp16, XOR-swizzled x-tile (16B-aligned b128 reads + conflict-free
//   stores; R4's stride-133 pad broke b128 alignment -> 22.4M conflict cycles).
// Then: h2 = relu(pull64(h1)+b1)@W2 ; h3 = relu(pull8(h2)+b2)@W3 ;
//       a3 = relu(pull4(h3)+b3) ; [mu|lv] = pull4(a3)@[Wmu|Wlv]+bias.

#define BSHIFT 7
#define BPB 128           // nodes per bucket
#define CAP 5632          // slots per bucket in pairs (avg 4096 + 24 sigma)
#define NBMAX 800         // >= NB = 782
#define CAPB 40           // LDS ring slots per bin (carry<=15 + round max ~25: P~1e-17)

// ---------------- partition: edges -> bucketed pairs ----------------
__global__ __launch_bounds__(1024) void k_part(const int* __restrict__ esrc, const int* __restrict__ edst,
                                               int* __restrict__ bcnt, int* __restrict__ pairs,
                                               int E, int NB, int nblocks) {
  __shared__ int bincnt[NBMAX];
  __shared__ int sflushed[NBMAX];
  __shared__ int binbuf[NBMAX * CAPB];
  const int tid = threadIdx.x;
  for (int b = tid; b < NB; b += 1024) { bincnt[b] = 0; sflushed[b] = 0; }
  __syncthreads();
  const int chunk = (E + nblocks - 1) / nblocks;
  const int e0 = blockIdx.x * chunk;
  const int e1 = min(e0 + chunk, E);
  for (int base = e0; base < e1; base += 1024) {
    int e = base + tid;
    if (e < e1) {
      int d = edst[e], s = esrc[e];
      int b = d >> BSHIFT;
      int pos = atomicAdd(&bincnt[b], 1);
      binbuf[b * CAPB + (pos % CAPB)] = (s << BSHIFT) | (d & (BPB - 1));
    }
    __syncthreads();
    if (tid < NB) {
      int c = bincnt[tid], f = sflushed[tid];
      while (c - f >= 16) {  // flush full 64B lines only
        int p = atomicAdd(&bcnt[tid * 16], 16);
#pragma unroll
        for (int j = 0; j < 16; ++j)
          pairs[(size_t)tid * CAP + p + j] = binbuf[tid * CAPB + ((f + j) % CAPB)];
        f += 16;
      }
      sflushed[tid] = f;
    }
    __syncthreads();
  }
  if (tid < NB) {  // drain partial lines (<=1 per bin per block)
    int c = bincnt[tid], f = sflushed[tid];
    int rem = c - f;
    if (rem > 0) {
      int p = atomicAdd(&bcnt[tid * 16], rem);
      for (int j = 0; j < rem; ++j)
        pairs[(size_t)tid * CAP + p + j] = binbuf[tid * CAPB + ((f + j) % CAPB)];
    }
  }
}

// ---------------- GEMM1: h1[n][64] = x[n][512] @ W1[512][64], fp16 out --------
// 256 thr = 128 nodes x 64 feats; thread: 4 nodes x 8 feats (acc[32]).
// xs XOR swizzle: word(k,node) = k*128 + (node ^ 8*((k>>2)&3)).
//   reads : float4 over nodes, 16B-aligned, words 0..127 permuted -> conflict-free
//   stores: bank = lrl + 8*(w ^ (lc&3)) -> all 32 banks, 2-way (free)
__global__ __launch_bounds__(256, 4) void k_gemm1(const float* __restrict__ x, const float* __restrict__ W,
                                                  __half* __restrict__ h1, int n) {
  __shared__ float xs[32 * 128];
  __shared__ float ws[32 * 64];
  const int tid = threadIdx.x;
  const int n0 = blockIdx.x * 128;
  const int tn = tid & 31;  // nodes tn*4 .. +3
  const int tf = tid >> 5;  // feats tf*8 .. +7
  const int lr = tid >> 3;  // 0..31
  const int lc = tid & 7;   // 0..7

  float4 px[4], pw[2];
  auto ldg_tile = [&](int kt) {
#pragma unroll
    for (int i = 0; i < 4; ++i) {
      int r = n0 + lr + i * 32;
      if (r >= n) r = n - 1;
      px[i] = *(const float4*)(x + (size_t)r * 512 + kt + lc * 4);
    }
#pragma unroll
    for (int i = 0; i < 2; ++i) {
      int idx = tid + 256 * i;
      int k = idx >> 4, f4 = idx & 15;
      pw[i] = *(const float4*)(W + (size_t)(kt + k) * 64 + f4 * 4);
    }
  };

  float acc[4][8];
#pragma unroll
  for (int i = 0; i < 4; ++i)
#pragma unroll
    for (int j = 0; j < 8; ++j) acc[i][j] = 0.f;

  ldg_tile(0);
  for (int t = 0; t < 16; ++t) {
    __syncthreads();
    {
      const int sw = 8 * (lc & 3);  // (k>>2)&3 == lc&3 for k = lc*4+j
#pragma unroll
      for (int i = 0; i < 4; ++i) {
        int r = (lr + i * 32) ^ sw;
        xs[(lc * 4 + 0) * 128 + r] = px[i].x;
        xs[(lc * 4 + 1) * 128 + r] = px[i].y;
        xs[(lc * 4 + 2) * 128 + r] = px[i].z;
        xs[(lc * 4 + 3) * 128 + r] = px[i].w;
      }
#pragma unroll
      for (int i = 0; i < 2; ++i) {
        int idx = tid + 256 * i;
        *(float4*)&ws[(idx >> 4) * 64 + (idx & 15) * 4] = pw[i];
      }
    }
    __syncthreads();
    if (t < 15) ldg_tile((t + 1) * 32);  // prefetch hides under MACs
#pragma unroll 8
    for (int k = 0; k < 32; ++k) {
      float4 xv = *(const float4*)&xs[k * 128 + ((tn * 4) ^ (8 * ((k >> 2) & 3)))];
      float4 w0 = *(const float4*)&ws[k * 64 + tf * 8];
      float4 w1 = *(const float4*)&ws[k * 64 + tf * 8 + 4];
      float xa[4] = {xv.x, xv.y, xv.z, xv.w};
      float wb[8] = {w0.x, w0.y, w0.z, w0.w, w1.x, w1.y, w1.z, w1.w};
#pragma unroll
      for (int i = 0; i < 4; ++i)
#pragma unroll
        for (int j = 0; j < 8; ++j) acc[i][j] = fmaf(xa[i], wb[j], acc[i][j]);
    }
  }
#pragma unroll
  for (int i = 0; i < 4; ++i) {
    int node = n0 + tn * 4 + i;
    if (node < n) {
      union { int4 v; __half h[8]; } u;
#pragma unroll
      for (int j = 0; j < 8; ++j) u.h[j] = __float2half_rn(acc[i][j]);
      *(int4*)(h1 + (size_t)node * 64 + tf * 8) = u.v;
    }
  }
}

// ---------------- bucket-size scan (one block) ----------------
__global__ __launch_bounds__(1024) void k_bscan(const int* __restrict__ bcnt, int* __restrict__ bbase,
                                                int* __restrict__ offs, int NB, int n, int E) {
  __shared__ int sc[1024];
  int tid = threadIdx.x;
  int v = (tid < NB) ? bcnt[tid * 16] : 0;
  sc[tid] = v;
  __syncthreads();
  for (int d = 1; d < 1024; d <<= 1) {
    int t = (tid >= d) ? sc[tid - d] : 0;
    __syncthreads();
    if (tid >= d) sc[tid] += t;
    __syncthreads();
  }
  if (tid < NB) bbase[tid] = sc[tid] - v;  // exclusive
  if (tid == 0) offs[n] = E;
}

// ---------------- per-bucket CSR finalize (also emits offs + dinv) -----------
__global__ __launch_bounds__(1024) void k_p2(const int* __restrict__ pairs, const int* __restrict__ bcnt,
                                             const int* __restrict__ bbase, int* __restrict__ offs,
                                             float* __restrict__ dinv, int* __restrict__ csr, int n) {
  __shared__ int lcnt[BPB];
  __shared__ int scanv[BPB];
  __shared__ int cur[BPB];
  __shared__ int sbuf[CAP];
  const int tid = threadIdx.x;
  const int b = blockIdx.x;
  const int size = bcnt[b * 16];
  const int base = bbase[b];
  const int node0 = b << BSHIFT;
  const int nb = min(BPB, n - node0);

  if (tid < BPB) lcnt[tid] = 0;
  __syncthreads();

  int stash[6];
  int ns = 0;
  for (int i = tid; i < size; i += 1024) {
    int w = pairs[(size_t)b * CAP + i];
    stash[ns++] = w;
    atomicAdd(&lcnt[w & (BPB - 1)], 1);
  }
  __syncthreads();
  if (tid < BPB) scanv[tid] = lcnt[tid];
  __syncthreads();
#pragma unroll
  for (int d = 1; d < BPB; d <<= 1) {
    int t = (tid < BPB && tid >= d) ? scanv[tid - d] : 0;
    __syncthreads();
    if (tid < BPB && tid >= d) scanv[tid] += t;
    __syncthreads();
  }
  if (tid < nb) {
    int excl = scanv[tid] - lcnt[tid];
    offs[node0 + tid] = base + excl;
    cur[tid] = excl;
    dinv[node0 + tid] = rsqrtf((float)(lcnt[tid] + 1));  // +1 self-loop
  }
  __syncthreads();
  for (int i = 0; i < ns; ++i) {
    int w = stash[i];
    int p = atomicAdd(&cur[w & (BPB - 1)], 1);
    sbuf[p] = w >> BSHIFT;
  }
  __syncthreads();
  for (int i = tid; i < size; i += 1024) csr[base + i] = sbuf[i];
}

// ---------------- pull64 (fp16 gather) + fused gemm2 ----------------
__global__ __launch_bounds__(256) void k_pull64(const __half* __restrict__ h, const int* __restrict__ offs,
                                                const int* __restrict__ csr, const float* __restrict__ dinv,
                                                const float* __restrict__ b1, const float* __restrict__ W2,
                                                float* __restrict__ h2, int n) {
  __shared__ float sa[4][64];
  __shared__ float w2s[512];
  const int tid = threadIdx.x;
  w2s[tid] = W2[tid];
  w2s[tid + 256] = W2[tid + 256];
  const int lane = tid & 63;
  const int wv = tid >> 6;
  const int node = blockIdx.x * 4 + wv;
  float a1v = 0.f;
  if (node < n) {
    int s0 = offs[node], s1 = offs[node + 1];
    float di = dinv[node];
    float acc = 0.f;
    int e = s0;
    for (; e + 4 <= s1; e += 4) {
      int i0 = csr[e], i1 = csr[e + 1], i2 = csr[e + 2], i3 = csr[e + 3];
      float w0 = dinv[i0], w1 = dinv[i1], w2 = dinv[i2], w3 = dinv[i3];
      float v0 = __half2float(h[(size_t)i0 * 64 + lane]);
      float v1 = __half2float(h[(size_t)i1 * 64 + lane]);
      float v2 = __half2float(h[(size_t)i2 * 64 + lane]);
      float v3 = __half2float(h[(size_t)i3 * 64 + lane]);
      acc = fmaf(w0, v0, acc); acc = fmaf(w1, v1, acc);
      acc = fmaf(w2, v2, acc); acc = fmaf(w3, v3, acc);
    }
    for (; e < s1; ++e) {
      int s = csr[e];
      acc = fmaf(dinv[s], __half2float(h[(size_t)s * 64 + lane]), acc);
    }
    acc = fmaf(di, __half2float(h[(size_t)node * 64 + lane]), acc);  // self-loop
    a1v = fmaxf(fmaf(di, acc, b1[lane]), 0.f);
  }
  sa[wv][lane] = a1v;
  __syncthreads();
  if (tid < 32) {
    int j = tid >> 3, f = tid & 7;
    int nd = blockIdx.x * 4 + j;
    if (nd < n) {
      float s = 0.f;
#pragma unroll
      for (int l = 0; l < 64; ++l) s = fmaf(sa[j][l], w2s[l * 8 + f], s);
      h2[(size_t)nd * 8 + f] = s;
    }
  }
}

// ---------------- pull8 + fused gemm3 ----------------
__global__ __launch_bounds__(256) void k_pull8(const float* __restrict__ h, const int* __restrict__ offs,
                                               const int* __restrict__ csr, const float* __restrict__ dinv,
                                               const float* __restrict__ b2, const float* __restrict__ W3,
                                               float* __restrict__ h3, int n) {
  __shared__ float sa[4][8];
  __shared__ float w3s[32];
  const int tid = threadIdx.x;
  if (tid < 32) w3s[tid] = W3[tid];
  const int lane = tid & 63;
  const int wv = tid >> 6;
  const int node = blockIdx.x * 4 + wv;
  const int j8 = lane >> 3, f = lane & 7;
  float pacc = 0.f;
  float di = 0.f;
  if (node < n) {
    int s0 = offs[node], s1 = offs[node + 1];
    di = dinv[node];
    for (int e0 = s0; e0 < s1; e0 += 8) {
      int e = e0 + j8;
      if (e < s1) {
        int s = csr[e];
        pacc = fmaf(dinv[s], h[(size_t)s * 8 + f], pacc);
      }
    }
  }
  pacc += __shfl_down(pacc, 32);
  pacc += __shfl_down(pacc, 16);
  pacc += __shfl_down(pacc, 8);
  if (node < n && lane < 8) {
    float v = pacc + di * h[(size_t)node * 8 + f];
    sa[wv][f] = fmaxf(fmaf(di, v, b2[f]), 0.f);
  }
  __syncthreads();
  if (tid < 16) {
    int j = tid >> 2, ff = tid & 3;
    int nd = blockIdx.x * 4 + j;
    if (nd < n) {
      float s = 0.f;
#pragma unroll
      for (int k = 0; k < 8; ++k) s = fmaf(sa[j][k], w3s[k * 4 + ff], s);
      h3[(size_t)nd * 4 + ff] = s;
    }
  }
}

// ---------------- pull4 (h3 -> a3, relu+bias) ----------------
__global__ __launch_bounds__(256) void k_pull4(const float* __restrict__ h, const int* __restrict__ offs,
                                               const int* __restrict__ csr, const float* __restrict__ dinv,
                                               const float* __restrict__ b3, float* __restrict__ out, int n) {
  const int tid = threadIdx.x;
  const int lane = tid & 63;
  const int node = blockIdx.x * 4 + (tid >> 6);
  if (node >= n) return;
  const int j16 = lane >> 2, f = lane & 3;
  int s0 = offs[node], s1 = offs[node + 1];
  float di = dinv[node];
  float pacc = 0.f;
  for (int e0 = s0; e0 < s1; e0 += 16) {
    int e = e0 + j16;
    if (e < s1) {
      int s = csr[e];
      pacc = fmaf(dinv[s], h[(size_t)s * 4 + f], pacc);
    }
  }
  pacc += __shfl_down(pacc, 32);
  pacc += __shfl_down(pacc, 16);
  pacc += __shfl_down(pacc, 8);
  pacc += __shfl_down(pacc, 4);
  if (lane < 4) {
    float v = pacc + di * h[(size_t)node * 4 + f];
    out[(size_t)node * 4 + f] = fmaxf(fmaf(di, v, b3[f]), 0.f);
  }
}

// ---------------- final pull4 + fused mu/lv heads ----------------
__global__ __launch_bounds__(256) void k_pull4o(const float* __restrict__ a3, const int* __restrict__ offs,
                                                const int* __restrict__ csr, const float* __restrict__ dinv,
                                                const float* __restrict__ Wmu, const float* __restrict__ bmu,
                                                const float* __restrict__ Wlv, const float* __restrict__ blv,
                                                float* __restrict__ outp, int n) {
  __shared__ float sg[4][4];
  const int tid = threadIdx.x;
  const int lane = tid & 63;
  const int wv = tid >> 6;
  const int node = blockIdx.x * 4 + wv;
  const int j16 = lane >> 2, f = lane & 3;
  float pacc = 0.f;
  float di = 0.f;
  if (node < n) {
    int s0 = offs[node], s1 = offs[node + 1];
    di = dinv[node];
    for (int e0 = s0; e0 < s1; e0 += 16) {
      int e = e0 + j16;
      if (e < s1) {
        int s = csr[e];
        pacc = fmaf(dinv[s], a3[(size_t)s * 4 + f], pacc);
      }
    }
  }
  pacc += __shfl_down(pacc, 32);
  pacc += __shfl_down(pacc, 16);
  pacc += __shfl_down(pacc, 8);
  pacc += __shfl_down(pacc, 4);
  if (node < n && lane < 4) {
    float v = pacc + di * a3[(size_t)node * 4 + f];
    sg[wv][f] = di * v;
  }
  __syncthreads();
  if (tid < 16) {
    int j = tid >> 2, c = tid & 3;  // c: 0=mu0 1=mu1 2=lv0 3=lv1
    int nd = blockIdx.x * 4 + j;
    if (nd < n) {
      const float* Wp = (c < 2) ? Wmu : Wlv;
      const float* bp = (c < 2) ? bmu : blv;
      int cc = c & 1;
      float s = bp[cc];
#pragma unroll
      for (int k = 0; k < 4; ++k) s = fmaf(sg[j][k], Wp[k * 2 + cc], s);
      size_t base = (c < 2) ? 0 : (size_t)2 * n;
      outp[base + (size_t)nd * 2 + cc] = s;
    }
  }
}

extern "C" void kernel_launch(void* const* d_in, const int* in_sizes, int n_in,
                              void* d_out, int out_size, void* d_ws, size_t ws_size,
                              hipStream_t stream) {
  const float* x = (const float*)d_in[0];
  const int* ei = (const int*)d_in[1];
  const float* W1 = (const float*)d_in[2];
  const float* b1 = (const float*)d_in[3];
  const float* W2 = (const float*)d_in[4];
  const float* b2 = (const float*)d_in[5];
  const float* W3 = (const float*)d_in[6];
  const float* b3 = (const float*)d_in[7];
  const float* Wmu = (const float*)d_in[8];
  const float* bmu = (const float*)d_in[9];
  const float* Wlv = (const float*)d_in[10];
  const float* blv = (const float*)d_in[11];
  float* out = (float*)d_out;

  const int N = in_sizes[0] / 512;
  const int E = in_sizes[1] / 2;
  const int* esrc = ei;
  const int* edst = ei + E;
  const int NB = (N + BPB - 1) >> BSHIFT;  // 782

  char* w = (char*)d_ws;
  size_t p = 0;
  auto alloc = [&](size_t bytes) -> void* {
    void* r = w + p;
    p = (p + bytes + 255) & ~(size_t)255;
    return r;
  };
  int* bcnt = (int*)alloc((size_t)NB * 16 * 4);  // 64B-padded counters
  int* bbase = (int*)alloc((size_t)NB * 4);
  int* offs = (int*)alloc((size_t)(N + 1) * 4);
  float* dinv = (float*)alloc((size_t)N * 4);
  int* csr = (int*)alloc((size_t)E * 4);
  int* pairs = (int*)alloc((size_t)NB * CAP * 4);
  __half* h1 = (__half*)alloc((size_t)N * 64 * 2);
  float* h2 = (float*)alloc((size_t)N * 8 * 4);
  float* h3 = (float*)alloc((size_t)N * 4 * 4);
  float* a3 = (float*)alloc((size_t)N * 4 * 4);

  hipMemsetAsync(bcnt, 0, (size_t)NB * 16 * 4, stream);

  k_part<<<256, 1024, 0, stream>>>(esrc, edst, bcnt, pairs, E, NB, 256);
  k_gemm1<<<(N + 127) / 128, 256, 0, stream>>>(x, W1, h1, N);
  k_bscan<<<1, 1024, 0, stream>>>(bcnt, bbase, offs, NB, N, E);
  k_p2<<<NB, 1024, 0, stream>>>(pairs, bcnt, bbase, offs, dinv, csr, N);

  k_pull64<<<(N + 3) / 4, 256, 0, stream>>>(h1, offs, csr, dinv, b1, h2 ? W2 : W2, h2, N);
  k_pull8<<<(N + 3) / 4, 256, 0, stream>>>(h2, offs, csr, dinv, b2, W3, h3, N);
  k_pull4<<<(N + 3) / 4, 256, 0, stream>>>(h3, offs, csr, dinv, b3, a3, N);
  k_pull4o<<<(N + 3) / 4, 256, 0, stream>>>(a3, offs, csr, dinv, Wmu, bmu, Wlv, blv, out, N);
}

// Round 2
// 627.206 us; speedup vs baseline: 1.0382x; 1.0382x over previous
//
#include <hip/hip_runtime.h>
#include <hip/hip_fp16.h>
#include <stdint.h>

// VGAE GCN encoder. CSR build via LDS-binned 2-phase bucket partition:
//   k_part: edges -> 782 buckets (128 dst-nodes each); per-block LDS rings of 40
//     slots/bucket, flushed in full 64B groups of 16 -> ~1x write amplification.
//   k_bscan: 782-entry exclusive scan -> bucket bases; offs[N]=E.
//   k_p2: per bucket: LDS degree count (emits offs+dinv), LDS rank, coalesced csr.
// k_gemm1m (R2): h1 = x@W1 via v_mfma_f32_16x16x32_f16, fp32 accumulate.
//   R1 counters: VALUBusy 40%, MfmaUtil 0, HBM 15.7%, occ 24.5% -> latency-bound
//   on the fp32-VALU floor (42us) at 132us. MFMA kills the compute floor; A-frags
//   read DIRECTLY from global x (16 rows x 128B segments/wave, each elem once) ->
//   no LDS/barriers; W preconverted once by k_wprep into B-frag order (64KB,
//   L2-resident, coalesced 1KB lines). Reg double-buffer prefetches step t+1.
// Then: h2 = relu(pull64(h1)+b1)@W2 ; h3 = relu(pull8(h2)+b2)@W3 ;
//       a3 = relu(pull4(h3)+b3) ; [mu|lv] = pull4(a3)@[Wmu|Wlv]+bias.

#define BSHIFT 7
#define BPB 128           // nodes per bucket
#define CAP 5632          // slots per bucket in pairs (avg 4096 + 24 sigma)
#define NBMAX 800         // >= NB = 782
#define CAPB 40           // LDS ring slots per bin

typedef _Float16 f16x8 __attribute__((ext_vector_type(8)));
typedef float f32x4 __attribute__((ext_vector_type(4)));

// ---------------- partition: edges -> bucketed pairs ----------------
__global__ __launch_bounds__(1024) void k_part(const int* __restrict__ esrc, const int* __restrict__ edst,
                                               int* __restrict__ bcnt, int* __restrict__ pairs,
                                               int E, int NB, int nblocks) {
  __shared__ int bincnt[NBMAX];
  __shared__ int sflushed[NBMAX];
  __shared__ int binbuf[NBMAX * CAPB];
  const int tid = threadIdx.x;
  for (int b = tid; b < NB; b += 1024) { bincnt[b] = 0; sflushed[b] = 0; }
  __syncthreads();
  const int chunk = (E + nblocks - 1) / nblocks;
  const int e0 = blockIdx.x * chunk;
  const int e1 = min(e0 + chunk, E);
  for (int base = e0; base < e1; base += 1024) {
    int e = base + tid;
    if (e < e1) {
      int d = edst[e], s = esrc[e];
      int b = d >> BSHIFT;
      int pos = atomicAdd(&bincnt[b], 1);
      binbuf[b * CAPB + (pos % CAPB)] = (s << BSHIFT) | (d & (BPB - 1));
    }
    __syncthreads();
    if (tid < NB) {
      int c = bincnt[tid], f = sflushed[tid];
      while (c - f >= 16) {  // flush full 64B lines only
        int p = atomicAdd(&bcnt[tid * 16], 16);
#pragma unroll
        for (int j = 0; j < 16; ++j)
          pairs[(size_t)tid * CAP + p + j] = binbuf[tid * CAPB + ((f + j) % CAPB)];
        f += 16;
      }
      sflushed[tid] = f;
    }
    __syncthreads();
  }
  if (tid < NB) {  // drain partial lines (<=1 per bin per block)
    int c = bincnt[tid], f = sflushed[tid];
    int rem = c - f;
    if (rem > 0) {
      int p = atomicAdd(&bcnt[tid * 16], rem);
      for (int j = 0; j < rem; ++j)
        pairs[(size_t)tid * CAP + p + j] = binbuf[tid * CAPB + ((f + j) % CAPB)];
    }
  }
}

// ---------------- W1 -> fp16 B-fragment layout ----------------
// wf[(s*4 + t)*64 + l][j] = W[s*32 + (l>>4)*8 + j][t*16 + (l&15)]
__global__ __launch_bounds__(256) void k_wprep(const float* __restrict__ W, _Float16* __restrict__ wf) {
  int idx = blockIdx.x * 256 + threadIdx.x;  // 0..4095
  int l = idx & 63, st = idx >> 6;
  int t = st & 3, s = st >> 2;
  int kg = l >> 4, c = l & 15;
  f16x8 v;
#pragma unroll
  for (int j = 0; j < 8; ++j)
    v[j] = (_Float16)W[(size_t)(s * 32 + kg * 8 + j) * 64 + t * 16 + c];
  *(f16x8*)(wf + (size_t)idx * 8) = v;
}

// ---------------- GEMM1 (MFMA): h1[n][64] = x[n][512] @ W1[512][64] ----------
// 256 thr = 4 independent waves; wave: 32 nodes x 64 feats (2 m-tiles x 4 n-tiles
// of 16x16x32 f16 MFMA). A from global fp32 (cvt in-reg), B from preconverted wf.
__global__ __launch_bounds__(256) void k_gemm1m(const float* __restrict__ x, const _Float16* __restrict__ wf,
                                                __half* __restrict__ h1, int n) {
  const int tid = threadIdx.x;
  const int lane = tid & 63;
  const int wv = tid >> 6;
  const int n0 = blockIdx.x * 128 + wv * 32;
  const int kg = lane >> 4;  // 0..3 (k-group)
  const int rr = lane & 15;  // row-in-tile / col-in-tile

  const float* xr0 = x + (size_t)min(n0 + rr, n - 1) * 512 + kg * 8;
  const float* xr1 = x + (size_t)min(n0 + 16 + rr, n - 1) * 512 + kg * 8;
  const f16x8* wfp = (const f16x8*)wf + lane;

  float4 abuf[2][2][2];  // [buf][m][half]
  f16x8 wbuf[2][4];      // [buf][n-tile]

  auto ldA = [&](float4 a[2][2], int t) {
    const int off = t * 32;
    a[0][0] = *(const float4*)(xr0 + off);
    a[0][1] = *(const float4*)(xr0 + off + 4);
    a[1][0] = *(const float4*)(xr1 + off);
    a[1][1] = *(const float4*)(xr1 + off + 4);
  };
  auto ldW = [&](f16x8 w[4], int t) {
#pragma unroll
    for (int j = 0; j < 4; ++j) w[j] = wfp[(t * 4 + j) * 64];
  };
  auto cvt8 = [&](const float4& lo, const float4& hi) -> f16x8 {
    f16x8 r;
    r[0] = (_Float16)lo.x; r[1] = (_Float16)lo.y; r[2] = (_Float16)lo.z; r[3] = (_Float16)lo.w;
    r[4] = (_Float16)hi.x; r[5] = (_Float16)hi.y; r[6] = (_Float16)hi.z; r[7] = (_Float16)hi.w;
    return r;
  };

  f32x4 acc[2][4];
#pragma unroll
  for (int m = 0; m < 2; ++m)
#pragma unroll
    for (int j = 0; j < 4; ++j) acc[m][j] = (f32x4){0.f, 0.f, 0.f, 0.f};

  ldA(abuf[0], 0);
  ldW(wbuf[0], 0);
#pragma unroll
  for (int t = 0; t < 16; ++t) {
    const int cur = t & 1, nxt = cur ^ 1;
    if (t + 1 < 16) {
      ldA(abuf[nxt], t + 1);
      ldW(wbuf[nxt], t + 1);
    }
    f16x8 am0 = cvt8(abuf[cur][0][0], abuf[cur][0][1]);
    f16x8 am1 = cvt8(abuf[cur][1][0], abuf[cur][1][1]);
#pragma unroll
    for (int j = 0; j < 4; ++j) {
      acc[0][j] = __builtin_amdgcn_mfma_f32_16x16x32_f16(am0, wbuf[cur][j], acc[0][j], 0, 0, 0);
      acc[1][j] = __builtin_amdgcn_mfma_f32_16x16x32_f16(am1, wbuf[cur][j], acc[1][j], 0, 0, 0);
    }
  }

  // D layout: node-sub-row = kg*4 + r, feat-col = rr (per 16x16 tile)
#pragma unroll
  for (int m = 0; m < 2; ++m)
#pragma unroll
    for (int r = 0; r < 4; ++r) {
      int node = n0 + m * 16 + kg * 4 + r;
      if (node < n) {
#pragma unroll
        for (int j = 0; j < 4; ++j)
          h1[(size_t)node * 64 + j * 16 + rr] = __float2half_rn(acc[m][j][r]);
      }
    }
}

// ---------------- bucket-size scan (one block) ----------------
__global__ __launch_bounds__(1024) void k_bscan(const int* __restrict__ bcnt, int* __restrict__ bbase,
                                                int* __restrict__ offs, int NB, int n, int E) {
  __shared__ int sc[1024];
  int tid = threadIdx.x;
  int v = (tid < NB) ? bcnt[tid * 16] : 0;
  sc[tid] = v;
  __syncthreads();
  for (int d = 1; d < 1024; d <<= 1) {
    int t = (tid >= d) ? sc[tid - d] : 0;
    __syncthreads();
    if (tid >= d) sc[tid] += t;
    __syncthreads();
  }
  if (tid < NB) bbase[tid] = sc[tid] - v;  // exclusive
  if (tid == 0) offs[n] = E;
}

// ---------------- per-bucket CSR finalize (also emits offs + dinv) -----------
__global__ __launch_bounds__(1024) void k_p2(const int* __restrict__ pairs, const int* __restrict__ bcnt,
                                             const int* __restrict__ bbase, int* __restrict__ offs,
                                             float* __restrict__ dinv, int* __restrict__ csr, int n) {
  __shared__ int lcnt[BPB];
  __shared__ int scanv[BPB];
  __shared__ int cur[BPB];
  __shared__ int sbuf[CAP];
  const int tid = threadIdx.x;
  const int b = blockIdx.x;
  const int size = bcnt[b * 16];
  const int base = bbase[b];
  const int node0 = b << BSHIFT;
  const int nb = min(BPB, n - node0);

  if (tid < BPB) lcnt[tid] = 0;
  __syncthreads();

  int stash[6];
  int ns = 0;
  for (int i = tid; i < size; i += 1024) {
    int w = pairs[(size_t)b * CAP + i];
    stash[ns++] = w;
    atomicAdd(&lcnt[w & (BPB - 1)], 1);
  }
  __syncthreads();
  if (tid < BPB) scanv[tid] = lcnt[tid];
  __syncthreads();
#pragma unroll
  for (int d = 1; d < BPB; d <<= 1) {
    int t = (tid < BPB && tid >= d) ? scanv[tid - d] : 0;
    __syncthreads();
    if (tid < BPB && tid >= d) scanv[tid] += t;
    __syncthreads();
  }
  if (tid < nb) {
    int excl = scanv[tid] - lcnt[tid];
    offs[node0 + tid] = base + excl;
    cur[tid] = excl;
    dinv[node0 + tid] = rsqrtf((float)(lcnt[tid] + 1));  // +1 self-loop
  }
  __syncthreads();
  for (int i = 0; i < ns; ++i) {
    int w = stash[i];
    int p = atomicAdd(&cur[w & (BPB - 1)], 1);
    sbuf[p] = w >> BSHIFT;
  }
  __syncthreads();
  for (int i = tid; i < size; i += 1024) csr[base + i] = sbuf[i];
}

// ---------------- pull64 (fp16 gather) + fused gemm2 ----------------
__global__ __launch_bounds__(256) void k_pull64(const __half* __restrict__ h, const int* __restrict__ offs,
                                                const int* __restrict__ csr, const float* __restrict__ dinv,
                                                const float* __restrict__ b1, const float* __restrict__ W2,
                                                float* __restrict__ h2, int n) {
  __shared__ float sa[4][64];
  __shared__ float w2s[512];
  const int tid = threadIdx.x;
  w2s[tid] = W2[tid];
  w2s[tid + 256] = W2[tid + 256];
  const int lane = tid & 63;
  const int wv = tid >> 6;
  const int node = blockIdx.x * 4 + wv;
  float a1v = 0.f;
  if (node < n) {
    int s0 = offs[node], s1 = offs[node + 1];
    float di = dinv[node];
    float acc = 0.f;
    int e = s0;
    for (; e + 4 <= s1; e += 4) {
      int i0 = csr[e], i1 = csr[e + 1], i2 = csr[e + 2], i3 = csr[e + 3];
      float w0 = dinv[i0], w1 = dinv[i1], w2 = dinv[i2], w3 = dinv[i3];
      float v0 = __half2float(h[(size_t)i0 * 64 + lane]);
      float v1 = __half2float(h[(size_t)i1 * 64 + lane]);
      float v2 = __half2float(h[(size_t)i2 * 64 + lane]);
      float v3 = __half2float(h[(size_t)i3 * 64 + lane]);
      acc = fmaf(w0, v0, acc); acc = fmaf(w1, v1, acc);
      acc = fmaf(w2, v2, acc); acc = fmaf(w3, v3, acc);
    }
    for (; e < s1; ++e) {
      int s = csr[e];
      acc = fmaf(dinv[s], __half2float(h[(size_t)s * 64 + lane]), acc);
    }
    acc = fmaf(di, __half2float(h[(size_t)node * 64 + lane]), acc);  // self-loop
    a1v = fmaxf(fmaf(di, acc, b1[lane]), 0.f);
  }
  sa[wv][lane] = a1v;
  __syncthreads();
  if (tid < 32) {
    int j = tid >> 3, f = tid & 7;
    int nd = blockIdx.x * 4 + j;
    if (nd < n) {
      float s = 0.f;
#pragma unroll
      for (int l = 0; l < 64; ++l) s = fmaf(sa[j][l], w2s[l * 8 + f], s);
      h2[(size_t)nd * 8 + f] = s;
    }
  }
}

// ---------------- pull8 + fused gemm3 ----------------
__global__ __launch_bounds__(256) void k_pull8(const float* __restrict__ h, const int* __restrict__ offs,
                                               const int* __restrict__ csr, const float* __restrict__ dinv,
                                               const float* __restrict__ b2, const float* __restrict__ W3,
                                               float* __restrict__ h3, int n) {
  __shared__ float sa[4][8];
  __shared__ float w3s[32];
  const int tid = threadIdx.x;
  if (tid < 32) w3s[tid] = W3[tid];
  const int lane = tid & 63;
  const int wv = tid >> 6;
  const int node = blockIdx.x * 4 + wv;
  const int j8 = lane >> 3, f = lane & 7;
  float pacc = 0.f;
  float di = 0.f;
  if (node < n) {
    int s0 = offs[node], s1 = offs[node + 1];
    di = dinv[node];
    for (int e0 = s0; e0 < s1; e0 += 8) {
      int e = e0 + j8;
      if (e < s1) {
        int s = csr[e];
        pacc = fmaf(dinv[s], h[(size_t)s * 8 + f], pacc);
      }
    }
  }
  pacc += __shfl_down(pacc, 32);
  pacc += __shfl_down(pacc, 16);
  pacc += __shfl_down(pacc, 8);
  if (node < n && lane < 8) {
    float v = pacc + di * h[(size_t)node * 8 + f];
    sa[wv][f] = fmaxf(fmaf(di, v, b2[f]), 0.f);
  }
  __syncthreads();
  if (tid < 16) {
    int j = tid >> 2, ff = tid & 3;
    int nd = blockIdx.x * 4 + j;
    if (nd < n) {
      float s = 0.f;
#pragma unroll
      for (int k = 0; k < 8; ++k) s = fmaf(sa[j][k], w3s[k * 4 + ff], s);
      h3[(size_t)nd * 4 + ff] = s;
    }
  }
}

// ---------------- pull4 (h3 -> a3, relu+bias) ----------------
__global__ __launch_bounds__(256) void k_pull4(const float* __restrict__ h, const int* __restrict__ offs,
                                               const int* __restrict__ csr, const float* __restrict__ dinv,
                                               const float* __restrict__ b3, float* __restrict__ out, int n) {
  const int tid = threadIdx.x;
  const int lane = tid & 63;
  const int node = blockIdx.x * 4 + (tid >> 6);
  if (node >= n) return;
  const int j16 = lane >> 2, f = lane & 3;
  int s0 = offs[node], s1 = offs[node + 1];
  float di = dinv[node];
  float pacc = 0.f;
  for (int e0 = s0; e0 < s1; e0 += 16) {
    int e = e0 + j16;
    if (e < s1) {
      int s = csr[e];
      pacc = fmaf(dinv[s], h[(size_t)s * 4 + f], pacc);
    }
  }
  pacc += __shfl_down(pacc, 32);
  pacc += __shfl_down(pacc, 16);
  pacc += __shfl_down(pacc, 8);
  pacc += __shfl_down(pacc, 4);
  if (lane < 4) {
    float v = pacc + di * h[(size_t)node * 4 + f];
    out[(size_t)node * 4 + f] = fmaxf(fmaf(di, v, b3[f]), 0.f);
  }
}

// ---------------- final pull4 + fused mu/lv heads ----------------
__global__ __launch_bounds__(256) void k_pull4o(const float* __restrict__ a3, const int* __restrict__ offs,
                                                const int* __restrict__ csr, const float* __restrict__ dinv,
                                                const float* __restrict__ Wmu, const float* __restrict__ bmu,
                                                const float* __restrict__ Wlv, const float* __restrict__ blv,
                                                float* __restrict__ outp, int n) {
  __shared__ float sg[4][4];
  const int tid = threadIdx.x;
  const int lane = tid & 63;
  const int wv = tid >> 6;
  const int node = blockIdx.x * 4 + wv;
  const int j16 = lane >> 2, f = lane & 3;
  float pacc = 0.f;
  float di = 0.f;
  if (node < n) {
    int s0 = offs[node], s1 = offs[node + 1];
    di = dinv[node];
    for (int e0 = s0; e0 < s1; e0 += 16) {
      int e = e0 + j16;
      if (e < s1) {
        int s = csr[e];
        pacc = fmaf(dinv[s], a3[(size_t)s * 4 + f], pacc);
      }
    }
  }
  pacc += __shfl_down(pacc, 32);
  pacc += __shfl_down(pacc, 16);
  pacc += __shfl_down(pacc, 8);
  pacc += __shfl_down(pacc, 4);
  if (node < n && lane < 4) {
    float v = pacc + di * a3[(size_t)node * 4 + f];
    sg[wv][f] = di * v;
  }
  __syncthreads();
  if (tid < 16) {
    int j = tid >> 2, c = tid & 3;  // c: 0=mu0 1=mu1 2=lv0 3=lv1
    int nd = blockIdx.x * 4 + j;
    if (nd < n) {
      const float* Wp = (c < 2) ? Wmu : Wlv;
      const float* bp = (c < 2) ? bmu : blv;
      int cc = c & 1;
      float s = bp[cc];
#pragma unroll
      for (int k = 0; k < 4; ++k) s = fmaf(sg[j][k], Wp[k * 2 + cc], s);
      size_t base = (c < 2) ? 0 : (size_t)2 * n;
      outp[base + (size_t)nd * 2 + cc] = s;
    }
  }
}

extern "C" void kernel_launch(void* const* d_in, const int* in_sizes, int n_in,
                              void* d_out, int out_size, void* d_ws, size_t ws_size,
                              hipStream_t stream) {
  const float* x = (const float*)d_in[0];
  const int* ei = (const int*)d_in[1];
  const float* W1 = (const float*)d_in[2];
  const float* b1 = (const float*)d_in[3];
  const float* W2 = (const float*)d_in[4];
  const float* b2 = (const float*)d_in[5];
  const float* W3 = (const float*)d_in[6];
  const float* b3 = (const float*)d_in[7];
  const float* Wmu = (const float*)d_in[8];
  const float* bmu = (const float*)d_in[9];
  const float* Wlv = (const float*)d_in[10];
  const float* blv = (const float*)d_in[11];
  float* out = (float*)d_out;

  const int N = in_sizes[0] / 512;
  const int E = in_sizes[1] / 2;
  const int* esrc = ei;
  const int* edst = ei + E;
  const int NB = (N + BPB - 1) >> BSHIFT;  // 782

  char* w = (char*)d_ws;
  size_t p = 0;
  auto alloc = [&](size_t bytes) -> void* {
    void* r = w + p;
    p = (p + bytes + 255) & ~(size_t)255;
    return r;
  };
  int* bcnt = (int*)alloc((size_t)NB * 16 * 4);  // 64B-padded counters
  int* bbase = (int*)alloc((size_t)NB * 4);
  int* offs = (int*)alloc((size_t)(N + 1) * 4);
  float* dinv = (float*)alloc((size_t)N * 4);
  int* csr = (int*)alloc((size_t)E * 4);
  int* pairs = (int*)alloc((size_t)NB * CAP * 4);
  __half* h1 = (__half*)alloc((size_t)N * 64 * 2);
  float* h2 = (float*)alloc((size_t)N * 8 * 4);
  float* h3 = (float*)alloc((size_t)N * 4 * 4);
  float* a3 = (float*)alloc((size_t)N * 4 * 4);
  _Float16* wf = (_Float16*)alloc((size_t)512 * 64 * 2);  // W1 fp16 frag layout

  hipMemsetAsync(bcnt, 0, (size_t)NB * 16 * 4, stream);

  k_wprep<<<16, 256, 0, stream>>>(W1, wf);
  k_part<<<256, 1024, 0, stream>>>(esrc, edst, bcnt, pairs, E, NB, 256);
  k_gemm1m<<<(N + 127) / 128, 256, 0, stream>>>(x, wf, h1, N);
  k_bscan<<<1, 1024, 0, stream>>>(bcnt, bbase, offs, NB, N, E);
  k_p2<<<NB, 1024, 0, stream>>>(pairs, bcnt, bbase, offs, dinv, csr, N);

  k_pull64<<<(N + 3) / 4, 256, 0, stream>>>(h1, offs, csr, dinv, b1, W2, h2, N);
  k_pull8<<<(N + 3) / 4, 256, 0, stream>>>(h2, offs, csr, dinv, b2, W3, h3, N);
  k_pull4<<<(N + 3) / 4, 256, 0, stream>>>(h3, offs, csr, dinv, b3, a3, N);
  k_pull4o<<<(N + 3) / 4, 256, 0, stream>>>(a3, offs, csr, dinv, Wmu, bmu, Wlv, blv, out, N);
}

// Round 3
// 587.249 us; speedup vs baseline: 1.1088x; 1.0680x over previous
//
#include <hip/hip_runtime.h>
#include <hip/hip_fp16.h>
#include <stdint.h>

// VGAE GCN encoder. CSR build via LDS-binned 2-phase bucket partition:
//   k_part: edges -> 782 buckets (128 dst-nodes each); LDS rings, 64B flushes.
//   k_bscan: 782-entry exclusive scan -> bucket bases; offs[N]=E.
//   k_p2: per bucket: LDS degree count (emits offs+dinv), LDS rank, coalesced csr.
// k_gemm1m: h1s = dinv*(x@W1) via v_mfma_f32_16x16x32_f16 (runs AFTER k_p2 so the
//   epilogue can prescale by dinv -> pulls need no per-edge dinv gather).
// R3: all activations stored PRESCALED by dinv (h1s,h2s,h3s,a3s). Pull loops are
//   pure "acc += row[src]" (R2 counters: pull64 120us, VALUBusy 39%, HBM 18% ->
//   latency+VALU bound on csr->dinv->h dependent gather chain).
//   pull64 packs 2 edges/instr: lane=(edge-half, feat-pair), 4B loads, float2 acc,
//   one cross-half shfl at the end. sa padded [4][65] (2.4M stride-64 conflicts).

#define BSHIFT 7
#define BPB 128           // nodes per bucket
#define CAP 5632          // slots per bucket in pairs (avg 4096 + 24 sigma)
#define NBMAX 800         // >= NB = 782
#define CAPB 40           // LDS ring slots per bin

typedef _Float16 f16x8 __attribute__((ext_vector_type(8)));
typedef float f32x4 __attribute__((ext_vector_type(4)));

// ---------------- partition: edges -> bucketed pairs ----------------
__global__ __launch_bounds__(1024) void k_part(const int* __restrict__ esrc, const int* __restrict__ edst,
                                               int* __restrict__ bcnt, int* __restrict__ pairs,
                                               int E, int NB, int nblocks) {
  __shared__ int bincnt[NBMAX];
  __shared__ int sflushed[NBMAX];
  __shared__ int binbuf[NBMAX * CAPB];
  const int tid = threadIdx.x;
  for (int b = tid; b < NB; b += 1024) { bincnt[b] = 0; sflushed[b] = 0; }
  __syncthreads();
  const int chunk = (E + nblocks - 1) / nblocks;
  const int e0 = blockIdx.x * chunk;
  const int e1 = min(e0 + chunk, E);
  for (int base = e0; base < e1; base += 1024) {
    int e = base + tid;
    if (e < e1) {
      int d = edst[e], s = esrc[e];
      int b = d >> BSHIFT;
      int pos = atomicAdd(&bincnt[b], 1);
      binbuf[b * CAPB + (pos % CAPB)] = (s << BSHIFT) | (d & (BPB - 1));
    }
    __syncthreads();
    if (tid < NB) {
      int c = bincnt[tid], f = sflushed[tid];
      while (c - f >= 16) {  // flush full 64B lines only
        int p = atomicAdd(&bcnt[tid * 16], 16);
#pragma unroll
        for (int j = 0; j < 16; ++j)
          pairs[(size_t)tid * CAP + p + j] = binbuf[tid * CAPB + ((f + j) % CAPB)];
        f += 16;
      }
      sflushed[tid] = f;
    }
    __syncthreads();
  }
  if (tid < NB) {  // drain partial lines (<=1 per bin per block)
    int c = bincnt[tid], f = sflushed[tid];
    int rem = c - f;
    if (rem > 0) {
      int p = atomicAdd(&bcnt[tid * 16], rem);
      for (int j = 0; j < rem; ++j)
        pairs[(size_t)tid * CAP + p + j] = binbuf[tid * CAPB + ((f + j) % CAPB)];
    }
  }
}

// ---------------- W1 -> fp16 B-fragment layout ----------------
// wf[(s*4 + t)*64 + l][j] = W[s*32 + (l>>4)*8 + j][t*16 + (l&15)]
__global__ __launch_bounds__(256) void k_wprep(const float* __restrict__ W, _Float16* __restrict__ wf) {
  int idx = blockIdx.x * 256 + threadIdx.x;  // 0..4095
  int l = idx & 63, st = idx >> 6;
  int t = st & 3, s = st >> 2;
  int kg = l >> 4, c = l & 15;
  f16x8 v;
#pragma unroll
  for (int j = 0; j < 8; ++j)
    v[j] = (_Float16)W[(size_t)(s * 32 + kg * 8 + j) * 64 + t * 16 + c];
  *(f16x8*)(wf + (size_t)idx * 8) = v;
}

// ---------------- GEMM1 (MFMA): h1s[n][64] = dinv*(x[n][512] @ W1[512][64]) ----
__global__ __launch_bounds__(256) void k_gemm1m(const float* __restrict__ x, const _Float16* __restrict__ wf,
                                                const float* __restrict__ dinv, __half* __restrict__ h1, int n) {
  const int tid = threadIdx.x;
  const int lane = tid & 63;
  const int wv = tid >> 6;
  const int n0 = blockIdx.x * 128 + wv * 32;
  const int kg = lane >> 4;  // 0..3 (k-group)
  const int rr = lane & 15;  // row-in-tile / col-in-tile

  const float* xr0 = x + (size_t)min(n0 + rr, n - 1) * 512 + kg * 8;
  const float* xr1 = x + (size_t)min(n0 + 16 + rr, n - 1) * 512 + kg * 8;
  const f16x8* wfp = (const f16x8*)wf + lane;

  float4 abuf[2][2][2];  // [buf][m][half]
  f16x8 wbuf[2][4];      // [buf][n-tile]

  auto ldA = [&](float4 a[2][2], int t) {
    const int off = t * 32;
    a[0][0] = *(const float4*)(xr0 + off);
    a[0][1] = *(const float4*)(xr0 + off + 4);
    a[1][0] = *(const float4*)(xr1 + off);
    a[1][1] = *(const float4*)(xr1 + off + 4);
  };
  auto ldW = [&](f16x8 w[4], int t) {
#pragma unroll
    for (int j = 0; j < 4; ++j) w[j] = wfp[(t * 4 + j) * 64];
  };
  auto cvt8 = [&](const float4& lo, const float4& hi) -> f16x8 {
    f16x8 r;
    r[0] = (_Float16)lo.x; r[1] = (_Float16)lo.y; r[2] = (_Float16)lo.z; r[3] = (_Float16)lo.w;
    r[4] = (_Float16)hi.x; r[5] = (_Float16)hi.y; r[6] = (_Float16)hi.z; r[7] = (_Float16)hi.w;
    return r;
  };

  f32x4 acc[2][4];
#pragma unroll
  for (int m = 0; m < 2; ++m)
#pragma unroll
    for (int j = 0; j < 4; ++j) acc[m][j] = (f32x4){0.f, 0.f, 0.f, 0.f};

  ldA(abuf[0], 0);
  ldW(wbuf[0], 0);
#pragma unroll
  for (int t = 0; t < 16; ++t) {
    const int cur = t & 1, nxt = cur ^ 1;
    if (t + 1 < 16) {
      ldA(abuf[nxt], t + 1);
      ldW(wbuf[nxt], t + 1);
    }
    f16x8 am0 = cvt8(abuf[cur][0][0], abuf[cur][0][1]);
    f16x8 am1 = cvt8(abuf[cur][1][0], abuf[cur][1][1]);
#pragma unroll
    for (int j = 0; j < 4; ++j) {
      acc[0][j] = __builtin_amdgcn_mfma_f32_16x16x32_f16(am0, wbuf[cur][j], acc[0][j], 0, 0, 0);
      acc[1][j] = __builtin_amdgcn_mfma_f32_16x16x32_f16(am1, wbuf[cur][j], acc[1][j], 0, 0, 0);
    }
  }

  // D layout: node-sub-row = kg*4 + r, feat-col = rr (per 16x16 tile)
#pragma unroll
  for (int m = 0; m < 2; ++m)
#pragma unroll
    for (int r = 0; r < 4; ++r) {
      int node = n0 + m * 16 + kg * 4 + r;
      if (node < n) {
        float di = dinv[node];
#pragma unroll
        for (int j = 0; j < 4; ++j)
          h1[(size_t)node * 64 + j * 16 + rr] = __float2half_rn(di * acc[m][j][r]);
      }
    }
}

// ---------------- bucket-size scan (one block) ----------------
__global__ __launch_bounds__(1024) void k_bscan(const int* __restrict__ bcnt, int* __restrict__ bbase,
                                                int* __restrict__ offs, int NB, int n, int E) {
  __shared__ int sc[1024];
  int tid = threadIdx.x;
  int v = (tid < NB) ? bcnt[tid * 16] : 0;
  sc[tid] = v;
  __syncthreads();
  for (int d = 1; d < 1024; d <<= 1) {
    int t = (tid >= d) ? sc[tid - d] : 0;
    __syncthreads();
    if (tid >= d) sc[tid] += t;
    __syncthreads();
  }
  if (tid < NB) bbase[tid] = sc[tid] - v;  // exclusive
  if (tid == 0) offs[n] = E;
}

// ---------------- per-bucket CSR finalize (also emits offs + dinv) -----------
__global__ __launch_bounds__(1024) void k_p2(const int* __restrict__ pairs, const int* __restrict__ bcnt,
                                             const int* __restrict__ bbase, int* __restrict__ offs,
                                             float* __restrict__ dinv, int* __restrict__ csr, int n) {
  __shared__ int lcnt[BPB];
  __shared__ int scanv[BPB];
  __shared__ int cur[BPB];
  __shared__ int sbuf[CAP];
  const int tid = threadIdx.x;
  const int b = blockIdx.x;
  const int size = bcnt[b * 16];
  const int base = bbase[b];
  const int node0 = b << BSHIFT;
  const int nb = min(BPB, n - node0);

  if (tid < BPB) lcnt[tid] = 0;
  __syncthreads();

  int stash[6];
  int ns = 0;
  for (int i = tid; i < size; i += 1024) {
    int w = pairs[(size_t)b * CAP + i];
    stash[ns++] = w;
    atomicAdd(&lcnt[w & (BPB - 1)], 1);
  }
  __syncthreads();
  if (tid < BPB) scanv[tid] = lcnt[tid];
  __syncthreads();
#pragma unroll
  for (int d = 1; d < BPB; d <<= 1) {
    int t = (tid < BPB && tid >= d) ? scanv[tid - d] : 0;
    __syncthreads();
    if (tid < BPB && tid >= d) scanv[tid] += t;
    __syncthreads();
  }
  if (tid < nb) {
    int excl = scanv[tid] - lcnt[tid];
    offs[node0 + tid] = base + excl;
    cur[tid] = excl;
    dinv[node0 + tid] = rsqrtf((float)(lcnt[tid] + 1));  // +1 self-loop
  }
  __syncthreads();
  for (int i = 0; i < ns; ++i) {
    int w = stash[i];
    int p = atomicAdd(&cur[w & (BPB - 1)], 1);
    sbuf[p] = w >> BSHIFT;
  }
  __syncthreads();
  for (int i = tid; i < size; i += 1024) csr[base + i] = sbuf[i];
}

// ---------------- pull64 (prescaled fp16, 2 edges/instr) + fused gemm2 -------
__global__ __launch_bounds__(256) void k_pull64(const __half* __restrict__ h, const int* __restrict__ offs,
                                                const int* __restrict__ csr, const float* __restrict__ dinv,
                                                const float* __restrict__ b1, const float* __restrict__ W2,
                                                float* __restrict__ h2, int n) {
  __shared__ float sa[4][65];
  __shared__ float w2s[512];
  const int tid = threadIdx.x;
  w2s[tid] = W2[tid];
  w2s[tid + 256] = W2[tid + 256];
  const int lane = tid & 63;
  const int wv = tid >> 6;
  const int node = blockIdx.x * 4 + wv;
  const int half = lane >> 5;   // which edge of the pair
  const int fp = lane & 31;     // feature pair 0..31
  const uint32_t* hp = (const uint32_t*)h;  // 2 fp16 per word
  float ax = 0.f, ay = 0.f;
  if (node < n) {
    const int s0 = offs[node], s1 = offs[node + 1];
    const int cnt = s1 - s0;
    auto acc1 = [&](int srcnode) {
      uint32_t v = hp[(size_t)srcnode * 32 + fp];
      __half2 hv = *(__half2*)&v;
      float2 f = __half22float2(hv);
      ax += f.x; ay += f.y;
    };
    int base = 0;
    for (; base + 8 <= cnt; base += 8) {  // 8 edges: 4 per half
      int e = s0 + base + half;
      int i0 = csr[e], i1 = csr[e + 2], i2 = csr[e + 4], i3 = csr[e + 6];
      acc1(i0); acc1(i1); acc1(i2); acc1(i3);
    }
    for (; base + 2 <= cnt; base += 2) {
      int e = s0 + base + half;
      acc1(csr[e]);
    }
    if (base < cnt && half == 0) acc1(csr[s0 + base]);  // odd tail on half 0
    if (half == 1) acc1(node);                          // self-loop on half 1
  }
  ax += __shfl_down(ax, 32);
  ay += __shfl_down(ay, 32);
  if (node < n && half == 0) {
    float di = dinv[node];
    float2 bb = *(const float2*)(b1 + 2 * fp);
    sa[wv][2 * fp + 0] = fmaxf(fmaf(di, ax, bb.x), 0.f);
    sa[wv][2 * fp + 1] = fmaxf(fmaf(di, ay, bb.y), 0.f);
  }
  __syncthreads();
  if (tid < 32) {
    int j = tid >> 3, f = tid & 7;
    int nd = blockIdx.x * 4 + j;
    if (nd < n) {
      float s = 0.f;
#pragma unroll
      for (int l = 0; l < 64; ++l) s = fmaf(sa[j][l], w2s[l * 8 + f], s);
      h2[(size_t)nd * 8 + f] = dinv[nd] * s;  // prescale for pull8
    }
  }
}

// ---------------- pull8 (prescaled) + fused gemm3 ----------------
__global__ __launch_bounds__(256) void k_pull8(const float* __restrict__ h, const int* __restrict__ offs,
                                               const int* __restrict__ csr, const float* __restrict__ dinv,
                                               const float* __restrict__ b2, const float* __restrict__ W3,
                                               float* __restrict__ h3, int n) {
  __shared__ float sa[4][8];
  __shared__ float w3s[32];
  const int tid = threadIdx.x;
  if (tid < 32) w3s[tid] = W3[tid];
  const int lane = tid & 63;
  const int wv = tid >> 6;
  const int node = blockIdx.x * 4 + wv;
  const int j8 = lane >> 3, f = lane & 7;
  float pacc = 0.f;
  if (node < n) {
    int s0 = offs[node], s1 = offs[node + 1];
    for (int e0 = s0; e0 < s1; e0 += 8) {
      int e = e0 + j8;
      if (e < s1) {
        int s = csr[e];
        pacc += h[(size_t)s * 8 + f];
      }
    }
  }
  pacc += __shfl_down(pacc, 32);
  pacc += __shfl_down(pacc, 16);
  pacc += __shfl_down(pacc, 8);
  if (node < n && lane < 8) {
    float v = pacc + h[(size_t)node * 8 + f];  // self-loop (prescaled)
    sa[wv][f] = fmaxf(fmaf(dinv[node], v, b2[f]), 0.f);
  }
  __syncthreads();
  if (tid < 16) {
    int j = tid >> 2, ff = tid & 3;
    int nd = blockIdx.x * 4 + j;
    if (nd < n) {
      float s = 0.f;
#pragma unroll
      for (int k = 0; k < 8; ++k) s = fmaf(sa[j][k], w3s[k * 4 + ff], s);
      h3[(size_t)nd * 4 + ff] = dinv[nd] * s;  // prescale for pull4
    }
  }
}

// ---------------- pull4 (prescaled h3 -> prescaled a3) ----------------
__global__ __launch_bounds__(256) void k_pull4(const float* __restrict__ h, const int* __restrict__ offs,
                                               const int* __restrict__ csr, const float* __restrict__ dinv,
                                               const float* __restrict__ b3, float* __restrict__ out, int n) {
  const int tid = threadIdx.x;
  const int lane = tid & 63;
  const int node = blockIdx.x * 4 + (tid >> 6);
  if (node >= n) return;
  const int j16 = lane >> 2, f = lane & 3;
  int s0 = offs[node], s1 = offs[node + 1];
  float pacc = 0.f;
  for (int e0 = s0; e0 < s1; e0 += 16) {
    int e = e0 + j16;
    if (e < s1) {
      int s = csr[e];
      pacc += h[(size_t)s * 4 + f];
    }
  }
  pacc += __shfl_down(pacc, 32);
  pacc += __shfl_down(pacc, 16);
  pacc += __shfl_down(pacc, 8);
  pacc += __shfl_down(pacc, 4);
  if (lane < 4) {
    float di = dinv[node];
    float v = pacc + h[(size_t)node * 4 + f];  // self-loop (prescaled)
    out[(size_t)node * 4 + f] = di * fmaxf(fmaf(di, v, b3[f]), 0.f);  // prescale for pull4o
  }
}

// ---------------- final pull4 (prescaled a3) + fused mu/lv heads -------------
__global__ __launch_bounds__(256) void k_pull4o(const float* __restrict__ a3, const int* __restrict__ offs,
                                                const int* __restrict__ csr, const float* __restrict__ dinv,
                                                const float* __restrict__ Wmu, const float* __restrict__ bmu,
                                                const float* __restrict__ Wlv, const float* __restrict__ blv,
                                                float* __restrict__ outp, int n) {
  __shared__ float sg[4][4];
  const int tid = threadIdx.x;
  const int lane = tid & 63;
  const int wv = tid >> 6;
  const int node = blockIdx.x * 4 + wv;
  const int j16 = lane >> 2, f = lane & 3;
  float pacc = 0.f;
  if (node < n) {
    int s0 = offs[node], s1 = offs[node + 1];
    for (int e0 = s0; e0 < s1; e0 += 16) {
      int e = e0 + j16;
      if (e < s1) {
        int s = csr[e];
        pacc += a3[(size_t)s * 4 + f];
      }
    }
  }
  pacc += __shfl_down(pacc, 32);
  pacc += __shfl_down(pacc, 16);
  pacc += __shfl_down(pacc, 8);
  pacc += __shfl_down(pacc, 4);
  if (node < n && lane < 4) {
    float v = pacc + a3[(size_t)node * 4 + f];  // self-loop (prescaled)
    sg[wv][f] = dinv[node] * v;
  }
  __syncthreads();
  if (tid < 16) {
    int j = tid >> 2, c = tid & 3;  // c: 0=mu0 1=mu1 2=lv0 3=lv1
    int nd = blockIdx.x * 4 + j;
    if (nd < n) {
      const float* Wp = (c < 2) ? Wmu : Wlv;
      const float* bp = (c < 2) ? bmu : blv;
      int cc = c & 1;
      float s = bp[cc];
#pragma unroll
      for (int k = 0; k < 4; ++k) s = fmaf(sg[j][k], Wp[k * 2 + cc], s);
      size_t base = (c < 2) ? 0 : (size_t)2 * n;
      outp[base + (size_t)nd * 2 + cc] = s;
    }
  }
}

extern "C" void kernel_launch(void* const* d_in, const int* in_sizes, int n_in,
                              void* d_out, int out_size, void* d_ws, size_t ws_size,
                              hipStream_t stream) {
  const float* x = (const float*)d_in[0];
  const int* ei = (const int*)d_in[1];
  const float* W1 = (const float*)d_in[2];
  const float* b1 = (const float*)d_in[3];
  const float* W2 = (const float*)d_in[4];
  const float* b2 = (const float*)d_in[5];
  const float* W3 = (const float*)d_in[6];
  const float* b3 = (const float*)d_in[7];
  const float* Wmu = (const float*)d_in[8];
  const float* bmu = (const float*)d_in[9];
  const float* Wlv = (const float*)d_in[10];
  const float* blv = (const float*)d_in[11];
  float* out = (float*)d_out;

  const int N = in_sizes[0] / 512;
  const int E = in_sizes[1] / 2;
  const int* esrc = ei;
  const int* edst = ei + E;
  const int NB = (N + BPB - 1) >> BSHIFT;  // 782

  char* w = (char*)d_ws;
  size_t p = 0;
  auto alloc = [&](size_t bytes) -> void* {
    void* r = w + p;
    p = (p + bytes + 255) & ~(size_t)255;
    return r;
  };
  int* bcnt = (int*)alloc((size_t)NB * 16 * 4);  // 64B-padded counters
  int* bbase = (int*)alloc((size_t)NB * 4);
  int* offs = (int*)alloc((size_t)(N + 1) * 4);
  float* dinv = (float*)alloc((size_t)N * 4);
  int* csr = (int*)alloc((size_t)E * 4);
  int* pairs = (int*)alloc((size_t)NB * CAP * 4);
  __half* h1 = (__half*)alloc((size_t)N * 64 * 2);
  float* h2 = (float*)alloc((size_t)N * 8 * 4);
  float* h3 = (float*)alloc((size_t)N * 4 * 4);
  float* a3 = (float*)alloc((size_t)N * 4 * 4);
  _Float16* wf = (_Float16*)alloc((size_t)512 * 64 * 2);  // W1 fp16 frag layout

  hipMemsetAsync(bcnt, 0, (size_t)NB * 16 * 4, stream);

  k_wprep<<<16, 256, 0, stream>>>(W1, wf);
  k_part<<<256, 1024, 0, stream>>>(esrc, edst, bcnt, pairs, E, NB, 256);
  k_bscan<<<1, 1024, 0, stream>>>(bcnt, bbase, offs, NB, N, E);
  k_p2<<<NB, 1024, 0, stream>>>(pairs, bcnt, bbase, offs, dinv, csr, N);
  k_gemm1m<<<(N + 127) / 128, 256, 0, stream>>>(x, wf, dinv, h1, N);  // after p2: dinv prescale

  k_pull64<<<(N + 3) / 4, 256, 0, stream>>>(h1, offs, csr, dinv, b1, W2, h2, N);
  k_pull8<<<(N + 3) / 4, 256, 0, stream>>>(h2, offs, csr, dinv, b2, W3, h3, N);
  k_pull4<<<(N + 3) / 4, 256, 0, stream>>>(h3, offs, csr, dinv, b3, a3, N);
  k_pull4o<<<(N + 3) / 4, 256, 0, stream>>>(a3, offs, csr, dinv, Wmu, bmu, Wlv, blv, out, N);
}

// Round 4
// 566.878 us; speedup vs baseline: 1.1487x; 1.0359x over previous
//
#include <hip/hip_runtime.h>
#include <hip/hip_fp16.h>
#include <stdint.h>

// VGAE GCN encoder. CSR build via LDS-binned 2-phase bucket partition:
//   k_part: edges -> 782 buckets (128 dst-nodes each); LDS rings, 64B flushes.
//   k_bscan: 782-entry exclusive scan -> bucket bases; offs[N]=E.
//   k_p2: per bucket: LDS degree count (emits offs+dinv), LDS rank, coalesced csr.
// k_gemm1m: h1s = dinv*(x@W1) via v_mfma_f32_16x16x32_f16.
//   R4: NAMED double-buffer regs + explicit 2-step loop (rule #20: runtime-indexed
//   ext_vector arrays [abuf[cur]] go to scratch if the 16-iter unroll fails ->
//   explains R2/R3 accounting showing gemm1m ~105us vs 33us stream floor).
// All activations PRESCALED by dinv (h1s,h2s,h3s,a3s): pulls are pure row sums.
// pull64 R4: 4 edges/gather-instr (lane=(q,f8), uint2=4 fp16/lane, 16 lanes/row),
//   16-edge groups -> 4 independent csr->row chains.

#define BSHIFT 7
#define BPB 128           // nodes per bucket
#define CAP 5632          // slots per bucket in pairs (avg 4096 + 24 sigma)
#define NBMAX 800         // >= NB = 782
#define CAPB 40           // LDS ring slots per bin

typedef _Float16 f16x8 __attribute__((ext_vector_type(8)));
typedef float f32x4 __attribute__((ext_vector_type(4)));

// ---------------- partition: edges -> bucketed pairs ----------------
__global__ __launch_bounds__(1024) void k_part(const int* __restrict__ esrc, const int* __restrict__ edst,
                                               int* __restrict__ bcnt, int* __restrict__ pairs,
                                               int E, int NB, int nblocks) {
  __shared__ int bincnt[NBMAX];
  __shared__ int sflushed[NBMAX];
  __shared__ int binbuf[NBMAX * CAPB];
  const int tid = threadIdx.x;
  for (int b = tid; b < NB; b += 1024) { bincnt[b] = 0; sflushed[b] = 0; }
  __syncthreads();
  const int chunk = (E + nblocks - 1) / nblocks;
  const int e0 = blockIdx.x * chunk;
  const int e1 = min(e0 + chunk, E);
  for (int base = e0; base < e1; base += 1024) {
    int e = base + tid;
    if (e < e1) {
      int d = edst[e], s = esrc[e];
      int b = d >> BSHIFT;
      int pos = atomicAdd(&bincnt[b], 1);
      binbuf[b * CAPB + (pos % CAPB)] = (s << BSHIFT) | (d & (BPB - 1));
    }
    __syncthreads();
    if (tid < NB) {
      int c = bincnt[tid], f = sflushed[tid];
      while (c - f >= 16) {  // flush full 64B lines only
        int p = atomicAdd(&bcnt[tid * 16], 16);
#pragma unroll
        for (int j = 0; j < 16; ++j)
          pairs[(size_t)tid * CAP + p + j] = binbuf[tid * CAPB + ((f + j) % CAPB)];
        f += 16;
      }
      sflushed[tid] = f;
    }
    __syncthreads();
  }
  if (tid < NB) {  // drain partial lines (<=1 per bin per block)
    int c = bincnt[tid], f = sflushed[tid];
    int rem = c - f;
    if (rem > 0) {
      int p = atomicAdd(&bcnt[tid * 16], rem);
      for (int j = 0; j < rem; ++j)
        pairs[(size_t)tid * CAP + p + j] = binbuf[tid * CAPB + ((f + j) % CAPB)];
    }
  }
}

// ---------------- W1 -> fp16 B-fragment layout ----------------
// wf[(s*4 + t)*64 + l][j] = W[s*32 + (l>>4)*8 + j][t*16 + (l&15)]
__global__ __launch_bounds__(256) void k_wprep(const float* __restrict__ W, _Float16* __restrict__ wf) {
  int idx = blockIdx.x * 256 + threadIdx.x;  // 0..4095
  int l = idx & 63, st = idx >> 6;
  int t = st & 3, s = st >> 2;
  int kg = l >> 4, c = l & 15;
  f16x8 v;
#pragma unroll
  for (int j = 0; j < 8; ++j)
    v[j] = (_Float16)W[(size_t)(s * 32 + kg * 8 + j) * 64 + t * 16 + c];
  *(f16x8*)(wf + (size_t)idx * 8) = v;
}

// ---------------- GEMM1 (MFMA): h1s[n][64] = dinv*(x[n][512] @ W1[512][64]) ----
// Named double-buffer (p*/q* A-regs, u*/v* W-regs) + explicit 2-step K-loop with
// peeled tail: every register index compile-time (rule #20 scratch avoidance).
#define LDA_P(t) { const int off = (t) * 32; \
  p0 = *(const float4*)(xr0 + off); p1 = *(const float4*)(xr0 + off + 4); \
  p2 = *(const float4*)(xr1 + off); p3 = *(const float4*)(xr1 + off + 4); }
#define LDA_Q(t) { const int off = (t) * 32; \
  q0 = *(const float4*)(xr0 + off); q1 = *(const float4*)(xr0 + off + 4); \
  q2 = *(const float4*)(xr1 + off); q3 = *(const float4*)(xr1 + off + 4); }
#define LDW_U(t) { u0 = wfp[((t) * 4 + 0) * 64]; u1 = wfp[((t) * 4 + 1) * 64]; \
                   u2 = wfp[((t) * 4 + 2) * 64]; u3 = wfp[((t) * 4 + 3) * 64]; }
#define LDW_V(t) { v0 = wfp[((t) * 4 + 0) * 64]; v1 = wfp[((t) * 4 + 1) * 64]; \
                   v2 = wfp[((t) * 4 + 2) * 64]; v3 = wfp[((t) * 4 + 3) * 64]; }
#define STEP_P() { f16x8 am0 = cvt8(p0, p1); f16x8 am1 = cvt8(p2, p3); \
  acc00 = __builtin_amdgcn_mfma_f32_16x16x32_f16(am0, u0, acc00, 0, 0, 0); \
  acc10 = __builtin_amdgcn_mfma_f32_16x16x32_f16(am1, u0, acc10, 0, 0, 0); \
  acc01 = __builtin_amdgcn_mfma_f32_16x16x32_f16(am0, u1, acc01, 0, 0, 0); \
  acc11 = __builtin_amdgcn_mfma_f32_16x16x32_f16(am1, u1, acc11, 0, 0, 0); \
  acc02 = __builtin_amdgcn_mfma_f32_16x16x32_f16(am0, u2, acc02, 0, 0, 0); \
  acc12 = __builtin_amdgcn_mfma_f32_16x16x32_f16(am1, u2, acc12, 0, 0, 0); \
  acc03 = __builtin_amdgcn_mfma_f32_16x16x32_f16(am0, u3, acc03, 0, 0, 0); \
  acc13 = __builtin_amdgcn_mfma_f32_16x16x32_f16(am1, u3, acc13, 0, 0, 0); }
#define STEP_Q() { f16x8 am0 = cvt8(q0, q1); f16x8 am1 = cvt8(q2, q3); \
  acc00 = __builtin_amdgcn_mfma_f32_16x16x32_f16(am0, v0, acc00, 0, 0, 0); \
  acc10 = __builtin_amdgcn_mfma_f32_16x16x32_f16(am1, v0, acc10, 0, 0, 0); \
  acc01 = __builtin_amdgcn_mfma_f32_16x16x32_f16(am0, v1, acc01, 0, 0, 0); \
  acc11 = __builtin_amdgcn_mfma_f32_16x16x32_f16(am1, v1, acc11, 0, 0, 0); \
  acc02 = __builtin_amdgcn_mfma_f32_16x16x32_f16(am0, v2, acc02, 0, 0, 0); \
  acc12 = __builtin_amdgcn_mfma_f32_16x16x32_f16(am1, v2, acc12, 0, 0, 0); \
  acc03 = __builtin_amdgcn_mfma_f32_16x16x32_f16(am0, v3, acc03, 0, 0, 0); \
  acc13 = __builtin_amdgcn_mfma_f32_16x16x32_f16(am1, v3, acc13, 0, 0, 0); }

__global__ __launch_bounds__(256) void k_gemm1m(const float* __restrict__ x, const _Float16* __restrict__ wf,
                                                const float* __restrict__ dinv, __half* __restrict__ h1, int n) {
  const int tid = threadIdx.x;
  const int lane = tid & 63;
  const int wv = tid >> 6;
  const int n0 = blockIdx.x * 128 + wv * 32;
  const int kg = lane >> 4;  // 0..3 (k-group)
  const int rr = lane & 15;  // row-in-tile / col-in-tile

  const float* xr0 = x + (size_t)min(n0 + rr, n - 1) * 512 + kg * 8;
  const float* xr1 = x + (size_t)min(n0 + 16 + rr, n - 1) * 512 + kg * 8;
  const f16x8* wfp = (const f16x8*)wf + lane;

  auto cvt8 = [&](const float4& lo, const float4& hi) -> f16x8 {
    f16x8 r;
    r[0] = (_Float16)lo.x; r[1] = (_Float16)lo.y; r[2] = (_Float16)lo.z; r[3] = (_Float16)lo.w;
    r[4] = (_Float16)hi.x; r[5] = (_Float16)hi.y; r[6] = (_Float16)hi.z; r[7] = (_Float16)hi.w;
    return r;
  };

  float4 p0, p1, p2, p3, q0, q1, q2, q3;
  f16x8 u0, u1, u2, u3, v0, v1, v2, v3;
  f32x4 acc00 = {0,0,0,0}, acc01 = {0,0,0,0}, acc02 = {0,0,0,0}, acc03 = {0,0,0,0};
  f32x4 acc10 = {0,0,0,0}, acc11 = {0,0,0,0}, acc12 = {0,0,0,0}, acc13 = {0,0,0,0};

  LDA_P(0); LDW_U(0);
  for (int t = 0; t < 14; t += 2) {
    LDA_Q(t + 1); LDW_V(t + 1);
    STEP_P();
    LDA_P(t + 2); LDW_U(t + 2);
    STEP_Q();
  }
  LDA_Q(15); LDW_V(15);
  STEP_P();  // t = 14
  STEP_Q();  // t = 15

  // D layout: node-sub-row = kg*4 + r, feat-col = rr (per 16x16 tile)
#pragma unroll
  for (int r = 0; r < 4; ++r) {
    int node = n0 + kg * 4 + r;
    if (node < n) {
      float di = dinv[node];
      h1[(size_t)node * 64 + 0 * 16 + rr] = __float2half_rn(di * acc00[r]);
      h1[(size_t)node * 64 + 1 * 16 + rr] = __float2half_rn(di * acc01[r]);
      h1[(size_t)node * 64 + 2 * 16 + rr] = __float2half_rn(di * acc02[r]);
      h1[(size_t)node * 64 + 3 * 16 + rr] = __float2half_rn(di * acc03[r]);
    }
  }
#pragma unroll
  for (int r = 0; r < 4; ++r) {
    int node = n0 + 16 + kg * 4 + r;
    if (node < n) {
      float di = dinv[node];
      h1[(size_t)node * 64 + 0 * 16 + rr] = __float2half_rn(di * acc10[r]);
      h1[(size_t)node * 64 + 1 * 16 + rr] = __float2half_rn(di * acc11[r]);
      h1[(size_t)node * 64 + 2 * 16 + rr] = __float2half_rn(di * acc12[r]);
      h1[(size_t)node * 64 + 3 * 16 + rr] = __float2half_rn(di * acc13[r]);
    }
  }
}

// ---------------- bucket-size scan (one block) ----------------
__global__ __launch_bounds__(1024) void k_bscan(const int* __restrict__ bcnt, int* __restrict__ bbase,
                                                int* __restrict__ offs, int NB, int n, int E) {
  __shared__ int sc[1024];
  int tid = threadIdx.x;
  int v = (tid < NB) ? bcnt[tid * 16] : 0;
  sc[tid] = v;
  __syncthreads();
  for (int d = 1; d < 1024; d <<= 1) {
    int t = (tid >= d) ? sc[tid - d] : 0;
    __syncthreads();
    if (tid >= d) sc[tid] += t;
    __syncthreads();
  }
  if (tid < NB) bbase[tid] = sc[tid] - v;  // exclusive
  if (tid == 0) offs[n] = E;
}

// ---------------- per-bucket CSR finalize (also emits offs + dinv) -----------
__global__ __launch_bounds__(1024) void k_p2(const int* __restrict__ pairs, const int* __restrict__ bcnt,
                                             const int* __restrict__ bbase, int* __restrict__ offs,
                                             float* __restrict__ dinv, int* __restrict__ csr, int n) {
  __shared__ int lcnt[BPB];
  __shared__ int scanv[BPB];
  __shared__ int cur[BPB];
  __shared__ int sbuf[CAP];
  const int tid = threadIdx.x;
  const int b = blockIdx.x;
  const int size = bcnt[b * 16];
  const int base = bbase[b];
  const int node0 = b << BSHIFT;
  const int nb = min(BPB, n - node0);

  if (tid < BPB) lcnt[tid] = 0;
  __syncthreads();

  int stash[6];
  int ns = 0;
  for (int i = tid; i < size; i += 1024) {
    int w = pairs[(size_t)b * CAP + i];
    stash[ns++] = w;
    atomicAdd(&lcnt[w & (BPB - 1)], 1);
  }
  __syncthreads();
  if (tid < BPB) scanv[tid] = lcnt[tid];
  __syncthreads();
#pragma unroll
  for (int d = 1; d < BPB; d <<= 1) {
    int t = (tid < BPB && tid >= d) ? scanv[tid - d] : 0;
    __syncthreads();
    if (tid < BPB && tid >= d) scanv[tid] += t;
    __syncthreads();
  }
  if (tid < nb) {
    int excl = scanv[tid] - lcnt[tid];
    offs[node0 + tid] = base + excl;
    cur[tid] = excl;
    dinv[node0 + tid] = rsqrtf((float)(lcnt[tid] + 1));  // +1 self-loop
  }
  __syncthreads();
  for (int i = 0; i < ns; ++i) {
    int w = stash[i];
    int p = atomicAdd(&cur[w & (BPB - 1)], 1);
    sbuf[p] = w >> BSHIFT;
  }
  __syncthreads();
  for (int i = tid; i < size; i += 1024) csr[base + i] = sbuf[i];
}

// ---------------- pull64 (prescaled fp16, 4 edges/instr) + fused gemm2 -------
__global__ __launch_bounds__(256) void k_pull64(const __half* __restrict__ h, const int* __restrict__ offs,
                                                const int* __restrict__ csr, const float* __restrict__ dinv,
                                                const float* __restrict__ b1, const float* __restrict__ W2,
                                                float* __restrict__ h2, int n) {
  __shared__ float sa[4][65];
  __shared__ float w2s[512];
  const int tid = threadIdx.x;
  w2s[tid] = W2[tid];
  w2s[tid + 256] = W2[tid + 256];
  const int lane = tid & 63;
  const int wv = tid >> 6;
  const int node = blockIdx.x * 4 + wv;
  const int q = lane >> 4;    // edge slot 0..3
  const int f8 = lane & 15;   // 8B chunk: feats f8*4 .. +3
  const uint2* hp = (const uint2*)h;  // row = 16 uint2
  float ax = 0.f, ay = 0.f, az = 0.f, aw = 0.f;
  if (node < n) {
    const int s0 = offs[node], s1 = offs[node + 1];
    const int cnt = s1 - s0;
    auto acc1 = [&](int src) {
      uint2 vv = hp[(size_t)src * 16 + f8];
      __half2 h0 = *(__half2*)&vv.x;
      __half2 h1v = *(__half2*)&vv.y;
      float2 f0 = __half22float2(h0);
      float2 f1 = __half22float2(h1v);
      ax += f0.x; ay += f0.y; az += f1.x; aw += f1.y;
    };
    int base = 0;
    for (; base + 16 <= cnt; base += 16) {  // 16 edges: 4 per quarter, 4 chains
      int e = s0 + base + q;
      int i0 = csr[e], i1 = csr[e + 4], i2 = csr[e + 8], i3 = csr[e + 12];
      acc1(i0); acc1(i1); acc1(i2); acc1(i3);
    }
    for (; base + 4 <= cnt; base += 4) acc1(csr[s0 + base + q]);
    if (base + q < cnt) acc1(csr[s0 + base + q]);  // tail 0..3
    if (q == 0) acc1(node);                        // self-loop once
  }
  ax += __shfl_down(ax, 32); ay += __shfl_down(ay, 32);
  az += __shfl_down(az, 32); aw += __shfl_down(aw, 32);
  ax += __shfl_down(ax, 16); ay += __shfl_down(ay, 16);
  az += __shfl_down(az, 16); aw += __shfl_down(aw, 16);
  if (node < n && lane < 16) {
    float di = dinv[node];
    float4 bb = *(const float4*)(b1 + 4 * f8);
    sa[wv][4 * f8 + 0] = fmaxf(fmaf(di, ax, bb.x), 0.f);
    sa[wv][4 * f8 + 1] = fmaxf(fmaf(di, ay, bb.y), 0.f);
    sa[wv][4 * f8 + 2] = fmaxf(fmaf(di, az, bb.z), 0.f);
    sa[wv][4 * f8 + 3] = fmaxf(fmaf(di, aw, bb.w), 0.f);
  }
  __syncthreads();
  if (tid < 32) {
    int j = tid >> 3, f = tid & 7;
    int nd = blockIdx.x * 4 + j;
    if (nd < n) {
      float s = 0.f;
#pragma unroll
      for (int l = 0; l < 64; ++l) s = fmaf(sa[j][l], w2s[l * 8 + f], s);
      h2[(size_t)nd * 8 + f] = dinv[nd] * s;  // prescale for pull8
    }
  }
}

// ---------------- pull8 (prescaled) + fused gemm3 ----------------
__global__ __launch_bounds__(256) void k_pull8(const float* __restrict__ h, const int* __restrict__ offs,
                                               const int* __restrict__ csr, const float* __restrict__ dinv,
                                               const float* __restrict__ b2, const float* __restrict__ W3,
                                               float* __restrict__ h3, int n) {
  __shared__ float sa[4][8];
  __shared__ float w3s[32];
  const int tid = threadIdx.x;
  if (tid < 32) w3s[tid] = W3[tid];
  const int lane = tid & 63;
  const int wv = tid >> 6;
  const int node = blockIdx.x * 4 + wv;
  const int j8 = lane >> 3, f = lane & 7;
  float pacc = 0.f;
  if (node < n) {
    int s0 = offs[node], s1 = offs[node + 1];
    for (int e0 = s0; e0 < s1; e0 += 8) {
      int e = e0 + j8;
      if (e < s1) {
        int s = csr[e];
        pacc += h[(size_t)s * 8 + f];
      }
    }
  }
  pacc += __shfl_down(pacc, 32);
  pacc += __shfl_down(pacc, 16);
  pacc += __shfl_down(pacc, 8);
  if (node < n && lane < 8) {
    float v = pacc + h[(size_t)node * 8 + f];  // self-loop (prescaled)
    sa[wv][f] = fmaxf(fmaf(dinv[node], v, b2[f]), 0.f);
  }
  __syncthreads();
  if (tid < 16) {
    int j = tid >> 2, ff = tid & 3;
    int nd = blockIdx.x * 4 + j;
    if (nd < n) {
      float s = 0.f;
#pragma unroll
      for (int k = 0; k < 8; ++k) s = fmaf(sa[j][k], w3s[k * 4 + ff], s);
      h3[(size_t)nd * 4 + ff] = dinv[nd] * s;  // prescale for pull4
    }
  }
}

// ---------------- pull4 (prescaled h3 -> prescaled a3) ----------------
__global__ __launch_bounds__(256) void k_pull4(const float* __restrict__ h, const int* __restrict__ offs,
                                               const int* __restrict__ csr, const float* __restrict__ dinv,
                                               const float* __restrict__ b3, float* __restrict__ out, int n) {
  const int tid = threadIdx.x;
  const int lane = tid & 63;
  const int node = blockIdx.x * 4 + (tid >> 6);
  if (node >= n) return;
  const int j16 = lane >> 2, f = lane & 3;
  int s0 = offs[node], s1 = offs[node + 1];
  float pacc = 0.f;
  for (int e0 = s0; e0 < s1; e0 += 16) {
    int e = e0 + j16;
    if (e < s1) {
      int s = csr[e];
      pacc += h[(size_t)s * 4 + f];
    }
  }
  pacc += __shfl_down(pacc, 32);
  pacc += __shfl_down(pacc, 16);
  pacc += __shfl_down(pacc, 8);
  pacc += __shfl_down(pacc, 4);
  if (lane < 4) {
    float di = dinv[node];
    float v = pacc + h[(size_t)node * 4 + f];  // self-loop (prescaled)
    out[(size_t)node * 4 + f] = di * fmaxf(fmaf(di, v, b3[f]), 0.f);  // prescale for pull4o
  }
}

// ---------------- final pull4 (prescaled a3) + fused mu/lv heads -------------
__global__ __launch_bounds__(256) void k_pull4o(const float* __restrict__ a3, const int* __restrict__ offs,
                                                const int* __restrict__ csr, const float* __restrict__ dinv,
                                                const float* __restrict__ Wmu, const float* __restrict__ bmu,
                                                const float* __restrict__ Wlv, const float* __restrict__ blv,
                                                float* __restrict__ outp, int n) {
  __shared__ float sg[4][4];
  const int tid = threadIdx.x;
  const int lane = tid & 63;
  const int wv = tid >> 6;
  const int node = blockIdx.x * 4 + wv;
  const int j16 = lane >> 2, f = lane & 3;
  float pacc = 0.f;
  if (node < n) {
    int s0 = offs[node], s1 = offs[node + 1];
    for (int e0 = s0; e0 < s1; e0 += 16) {
      int e = e0 + j16;
      if (e < s1) {
        int s = csr[e];
        pacc += a3[(size_t)s * 4 + f];
      }
    }
  }
  pacc += __shfl_down(pacc, 32);
  pacc += __shfl_down(pacc, 16);
  pacc += __shfl_down(pacc, 8);
  pacc += __shfl_down(pacc, 4);
  if (node < n && lane < 4) {
    float v = pacc + a3[(size_t)node * 4 + f];  // self-loop (prescaled)
    sg[wv][f] = dinv[node] * v;
  }
  __syncthreads();
  if (tid < 16) {
    int j = tid >> 2, c = tid & 3;  // c: 0=mu0 1=mu1 2=lv0 3=lv1
    int nd = blockIdx.x * 4 + j;
    if (nd < n) {
      const float* Wp = (c < 2) ? Wmu : Wlv;
      const float* bp = (c < 2) ? bmu : blv;
      int cc = c & 1;
      float s = bp[cc];
#pragma unroll
      for (int k = 0; k < 4; ++k) s = fmaf(sg[j][k], Wp[k * 2 + cc], s);
      size_t base = (c < 2) ? 0 : (size_t)2 * n;
      outp[base + (size_t)nd * 2 + cc] = s;
    }
  }
}

extern "C" void kernel_launch(void* const* d_in, const int* in_sizes, int n_in,
                              void* d_out, int out_size, void* d_ws, size_t ws_size,
                              hipStream_t stream) {
  const float* x = (const float*)d_in[0];
  const int* ei = (const int*)d_in[1];
  const float* W1 = (const float*)d_in[2];
  const float* b1 = (const float*)d_in[3];
  const float* W2 = (const float*)d_in[4];
  const float* b2 = (const float*)d_in[5];
  const float* W3 = (const float*)d_in[6];
  const float* b3 = (const float*)d_in[7];
  const float* Wmu = (const float*)d_in[8];
  const float* bmu = (const float*)d_in[9];
  const float* Wlv = (const float*)d_in[10];
  const float* blv = (const float*)d_in[11];
  float* out = (float*)d_out;

  const int N = in_sizes[0] / 512;
  const int E = in_sizes[1] / 2;
  const int* esrc = ei;
  const int* edst = ei + E;
  const int NB = (N + BPB - 1) >> BSHIFT;  // 782

  char* w = (char*)d_ws;
  size_t p = 0;
  auto alloc = [&](size_t bytes) -> void* {
    void* r = w + p;
    p = (p + bytes + 255) & ~(size_t)255;
    return r;
  };
  int* bcnt = (int*)alloc((size_t)NB * 16 * 4);  // 64B-padded counters
  int* bbase = (int*)alloc((size_t)NB * 4);
  int* offs = (int*)alloc((size_t)(N + 1) * 4);
  float* dinv = (float*)alloc((size_t)N * 4);
  int* csr = (int*)alloc((size_t)E * 4);
  int* pairs = (int*)alloc((size_t)NB * CAP * 4);
  __half* h1 = (__half*)alloc((size_t)N * 64 * 2);
  float* h2 = (float*)alloc((size_t)N * 8 * 4);
  float* h3 = (float*)alloc((size_t)N * 4 * 4);
  float* a3 = (float*)alloc((size_t)N * 4 * 4);
  _Float16* wf = (_Float16*)alloc((size_t)512 * 64 * 2);  // W1 fp16 frag layout

  hipMemsetAsync(bcnt, 0, (size_t)NB * 16 * 4, stream);

  k_wprep<<<16, 256, 0, stream>>>(W1, wf);
  k_part<<<256, 1024, 0, stream>>>(esrc, edst, bcnt, pairs, E, NB, 256);
  k_bscan<<<1, 1024, 0, stream>>>(bcnt, bbase, offs, NB, N, E);
  k_p2<<<NB, 1024, 0, stream>>>(pairs, bcnt, bbase, offs, dinv, csr, N);
  k_gemm1m<<<(N + 127) / 128, 256, 0, stream>>>(x, wf, dinv, h1, N);  // after p2: dinv prescale

  k_pull64<<<(N + 3) / 4, 256, 0, stream>>>(h1, offs, csr, dinv, b1, W2, h2, N);
  k_pull8<<<(N + 3) / 4, 256, 0, stream>>>(h2, offs, csr, dinv, b2, W3, h3, N);
  k_pull4<<<(N + 3) / 4, 256, 0, stream>>>(h3, offs, csr, dinv, b3, a3, N);
  k_pull4o<<<(N + 3) / 4, 256, 0, stream>>>(a3, offs, csr, dinv, Wmu, bmu, Wlv, blv, out, N);
}

// Round 5
// 552.402 us; speedup vs baseline: 1.1788x; 1.0262x over previous
//
#include <hip/hip_runtime.h>
#include <hip/hip_fp16.h>
#include <stdint.h>

// VGAE GCN encoder. CSR build via LDS-binned 2-phase bucket partition:
//   k_part: edges -> 782 buckets (128 dst-nodes each); LDS rings, 64B flushes.
//   k_bscan: 782-entry exclusive scan -> bucket bases; offs[N]=E.
//   k_p2 (R5): rank captured from the COUNT pass's atomicAdd return value ->
//     second atomic pass deleted (placement is a pure LDS write). CSR within-bin
//     order = atomic grant order (permutation; sums order-independent).
// k_gemm1m: h1s = dinv*(x@W1) via v_mfma_f32_16x16x32_f16, named dbuf regs.
// All activations PRESCALED by dinv (h1s,h2s,h3s,a3s): pulls are pure row sums.
// pull64: 4 edges/gather-instr (lane=(q,f8), uint2, 16 lanes/row).
// pull8/pull4/pull4o (R5): 2 independent csr->h gather chains (deg~32 was a
//   serial 4/2/2-deep latency chain; 2-deep halves it).

#define BSHIFT 7
#define BPB 128           // nodes per bucket
#define CAP 5632          // slots per bucket in pairs (avg 4096 + 24 sigma)
#define NBMAX 800         // >= NB = 782
#define CAPB 40           // LDS ring slots per bin

typedef _Float16 f16x8 __attribute__((ext_vector_type(8)));
typedef float f32x4 __attribute__((ext_vector_type(4)));

// ---------------- partition: edges -> bucketed pairs ----------------
__global__ __launch_bounds__(1024) void k_part(const int* __restrict__ esrc, const int* __restrict__ edst,
                                               int* __restrict__ bcnt, int* __restrict__ pairs,
                                               int E, int NB, int nblocks) {
  __shared__ int bincnt[NBMAX];
  __shared__ int sflushed[NBMAX];
  __shared__ int binbuf[NBMAX * CAPB];
  const int tid = threadIdx.x;
  for (int b = tid; b < NB; b += 1024) { bincnt[b] = 0; sflushed[b] = 0; }
  __syncthreads();
  const int chunk = (E + nblocks - 1) / nblocks;
  const int e0 = blockIdx.x * chunk;
  const int e1 = min(e0 + chunk, E);
  for (int base = e0; base < e1; base += 1024) {
    int e = base + tid;
    if (e < e1) {
      int d = edst[e], s = esrc[e];
      int b = d >> BSHIFT;
      int pos = atomicAdd(&bincnt[b], 1);
      binbuf[b * CAPB + (pos % CAPB)] = (s << BSHIFT) | (d & (BPB - 1));
    }
    __syncthreads();
    if (tid < NB) {
      int c = bincnt[tid], f = sflushed[tid];
      while (c - f >= 16) {  // flush full 64B lines only
        int p = atomicAdd(&bcnt[tid * 16], 16);
#pragma unroll
        for (int j = 0; j < 16; ++j)
          pairs[(size_t)tid * CAP + p + j] = binbuf[tid * CAPB + ((f + j) % CAPB)];
        f += 16;
      }
      sflushed[tid] = f;
    }
    __syncthreads();
  }
  if (tid < NB) {  // drain partial lines (<=1 per bin per block)
    int c = bincnt[tid], f = sflushed[tid];
    int rem = c - f;
    if (rem > 0) {
      int p = atomicAdd(&bcnt[tid * 16], rem);
      for (int j = 0; j < rem; ++j)
        pairs[(size_t)tid * CAP + p + j] = binbuf[tid * CAPB + ((f + j) % CAPB)];
    }
  }
}

// ---------------- W1 -> fp16 B-fragment layout ----------------
// wf[(s*4 + t)*64 + l][j] = W[s*32 + (l>>4)*8 + j][t*16 + (l&15)]
__global__ __launch_bounds__(256) void k_wprep(const float* __restrict__ W, _Float16* __restrict__ wf) {
  int idx = blockIdx.x * 256 + threadIdx.x;  // 0..4095
  int l = idx & 63, st = idx >> 6;
  int t = st & 3, s = st >> 2;
  int kg = l >> 4, c = l & 15;
  f16x8 v;
#pragma unroll
  for (int j = 0; j < 8; ++j)
    v[j] = (_Float16)W[(size_t)(s * 32 + kg * 8 + j) * 64 + t * 16 + c];
  *(f16x8*)(wf + (size_t)idx * 8) = v;
}

// ---------------- GEMM1 (MFMA): h1s[n][64] = dinv*(x[n][512] @ W1[512][64]) ----
// Named double-buffer (p*/q* A-regs, u*/v* W-regs) + explicit 2-step K-loop with
// peeled tail: every register index compile-time (rule #20 scratch avoidance).
#define LDA_P(t) { const int off = (t) * 32; \
  p0 = *(const float4*)(xr0 + off); p1 = *(const float4*)(xr0 + off + 4); \
  p2 = *(const float4*)(xr1 + off); p3 = *(const float4*)(xr1 + off + 4); }
#define LDA_Q(t) { const int off = (t) * 32; \
  q0 = *(const float4*)(xr0 + off); q1 = *(const float4*)(xr0 + off + 4); \
  q2 = *(const float4*)(xr1 + off); q3 = *(const float4*)(xr1 + off + 4); }
#define LDW_U(t) { u0 = wfp[((t) * 4 + 0) * 64]; u1 = wfp[((t) * 4 + 1) * 64]; \
                   u2 = wfp[((t) * 4 + 2) * 64]; u3 = wfp[((t) * 4 + 3) * 64]; }
#define LDW_V(t) { v0 = wfp[((t) * 4 + 0) * 64]; v1 = wfp[((t) * 4 + 1) * 64]; \
                   v2 = wfp[((t) * 4 + 2) * 64]; v3 = wfp[((t) * 4 + 3) * 64]; }
#define STEP_P() { f16x8 am0 = cvt8(p0, p1); f16x8 am1 = cvt8(p2, p3); \
  acc00 = __builtin_amdgcn_mfma_f32_16x16x32_f16(am0, u0, acc00, 0, 0, 0); \
  acc10 = __builtin_amdgcn_mfma_f32_16x16x32_f16(am1, u0, acc10, 0, 0, 0); \
  acc01 = __builtin_amdgcn_mfma_f32_16x16x32_f16(am0, u1, acc01, 0, 0, 0); \
  acc11 = __builtin_amdgcn_mfma_f32_16x16x32_f16(am1, u1, acc11, 0, 0, 0); \
  acc02 = __builtin_amdgcn_mfma_f32_16x16x32_f16(am0, u2, acc02, 0, 0, 0); \
  acc12 = __builtin_amdgcn_mfma_f32_16x16x32_f16(am1, u2, acc12, 0, 0, 0); \
  acc03 = __builtin_amdgcn_mfma_f32_16x16x32_f16(am0, u3, acc03, 0, 0, 0); \
  acc13 = __builtin_amdgcn_mfma_f32_16x16x32_f16(am1, u3, acc13, 0, 0, 0); }
#define STEP_Q() { f16x8 am0 = cvt8(q0, q1); f16x8 am1 = cvt8(q2, q3); \
  acc00 = __builtin_amdgcn_mfma_f32_16x16x32_f16(am0, v0, acc00, 0, 0, 0); \
  acc10 = __builtin_amdgcn_mfma_f32_16x16x32_f16(am1, v0, acc10, 0, 0, 0); \
  acc01 = __builtin_amdgcn_mfma_f32_16x16x32_f16(am0, v1, acc01, 0, 0, 0); \
  acc11 = __builtin_amdgcn_mfma_f32_16x16x32_f16(am1, v1, acc11, 0, 0, 0); \
  acc02 = __builtin_amdgcn_mfma_f32_16x16x32_f16(am0, v2, acc02, 0, 0, 0); \
  acc12 = __builtin_amdgcn_mfma_f32_16x16x32_f16(am1, v2, acc12, 0, 0, 0); \
  acc03 = __builtin_amdgcn_mfma_f32_16x16x32_f16(am0, v3, acc03, 0, 0, 0); \
  acc13 = __builtin_amdgcn_mfma_f32_16x16x32_f16(am1, v3, acc13, 0, 0, 0); }

__global__ __launch_bounds__(256) void k_gemm1m(const float* __restrict__ x, const _Float16* __restrict__ wf,
                                                const float* __restrict__ dinv, __half* __restrict__ h1, int n) {
  const int tid = threadIdx.x;
  const int lane = tid & 63;
  const int wv = tid >> 6;
  const int n0 = blockIdx.x * 128 + wv * 32;
  const int kg = lane >> 4;  // 0..3 (k-group)
  const int rr = lane & 15;  // row-in-tile / col-in-tile

  const float* xr0 = x + (size_t)min(n0 + rr, n - 1) * 512 + kg * 8;
  const float* xr1 = x + (size_t)min(n0 + 16 + rr, n - 1) * 512 + kg * 8;
  const f16x8* wfp = (const f16x8*)wf + lane;

  auto cvt8 = [&](const float4& lo, const float4& hi) -> f16x8 {
    f16x8 r;
    r[0] = (_Float16)lo.x; r[1] = (_Float16)lo.y; r[2] = (_Float16)lo.z; r[3] = (_Float16)lo.w;
    r[4] = (_Float16)hi.x; r[5] = (_Float16)hi.y; r[6] = (_Float16)hi.z; r[7] = (_Float16)hi.w;
    return r;
  };

  float4 p0, p1, p2, p3, q0, q1, q2, q3;
  f16x8 u0, u1, u2, u3, v0, v1, v2, v3;
  f32x4 acc00 = {0,0,0,0}, acc01 = {0,0,0,0}, acc02 = {0,0,0,0}, acc03 = {0,0,0,0};
  f32x4 acc10 = {0,0,0,0}, acc11 = {0,0,0,0}, acc12 = {0,0,0,0}, acc13 = {0,0,0,0};

  LDA_P(0); LDW_U(0);
  for (int t = 0; t < 14; t += 2) {
    LDA_Q(t + 1); LDW_V(t + 1);
    STEP_P();
    LDA_P(t + 2); LDW_U(t + 2);
    STEP_Q();
  }
  LDA_Q(15); LDW_V(15);
  STEP_P();  // t = 14
  STEP_Q();  // t = 15

  // D layout: node-sub-row = kg*4 + r, feat-col = rr (per 16x16 tile)
#pragma unroll
  for (int r = 0; r < 4; ++r) {
    int node = n0 + kg * 4 + r;
    if (node < n) {
      float di = dinv[node];
      h1[(size_t)node * 64 + 0 * 16 + rr] = __float2half_rn(di * acc00[r]);
      h1[(size_t)node * 64 + 1 * 16 + rr] = __float2half_rn(di * acc01[r]);
      h1[(size_t)node * 64 + 2 * 16 + rr] = __float2half_rn(di * acc02[r]);
      h1[(size_t)node * 64 + 3 * 16 + rr] = __float2half_rn(di * acc03[r]);
    }
  }
#pragma unroll
  for (int r = 0; r < 4; ++r) {
    int node = n0 + 16 + kg * 4 + r;
    if (node < n) {
      float di = dinv[node];
      h1[(size_t)node * 64 + 0 * 16 + rr] = __float2half_rn(di * acc10[r]);
      h1[(size_t)node * 64 + 1 * 16 + rr] = __float2half_rn(di * acc11[r]);
      h1[(size_t)node * 64 + 2 * 16 + rr] = __float2half_rn(di * acc12[r]);
      h1[(size_t)node * 64 + 3 * 16 + rr] = __float2half_rn(di * acc13[r]);
    }
  }
}

// ---------------- bucket-size scan (one block) ----------------
__global__ __launch_bounds__(1024) void k_bscan(const int* __restrict__ bcnt, int* __restrict__ bbase,
                                                int* __restrict__ offs, int NB, int n, int E) {
  __shared__ int sc[1024];
  int tid = threadIdx.x;
  int v = (tid < NB) ? bcnt[tid * 16] : 0;
  sc[tid] = v;
  __syncthreads();
  for (int d = 1; d < 1024; d <<= 1) {
    int t = (tid >= d) ? sc[tid - d] : 0;
    __syncthreads();
    if (tid >= d) sc[tid] += t;
    __syncthreads();
  }
  if (tid < NB) bbase[tid] = sc[tid] - v;  // exclusive
  if (tid == 0) offs[n] = E;
}

// ---------------- per-bucket CSR finalize (also emits offs + dinv) -----------
// R5: rank captured from the count-pass atomicAdd (pass 2 is atomic-free).
__global__ __launch_bounds__(1024) void k_p2(const int* __restrict__ pairs, const int* __restrict__ bcnt,
                                             const int* __restrict__ bbase, int* __restrict__ offs,
                                             float* __restrict__ dinv, int* __restrict__ csr, int n) {
  __shared__ int lcnt[BPB];
  __shared__ int excl[BPB];
  __shared__ int sbuf[CAP];
  const int tid = threadIdx.x;
  const int b = blockIdx.x;
  const int size = bcnt[b * 16];
  const int base = bbase[b];
  const int node0 = b << BSHIFT;
  const int nb = min(BPB, n - node0);

  if (tid < BPB) lcnt[tid] = 0;
  __syncthreads();

  int stash[6];
  int rank[6];
  int ns = 0;
  for (int i = tid; i < size; i += 1024) {
    int w = pairs[(size_t)b * CAP + i];
    stash[ns] = w;
    rank[ns] = atomicAdd(&lcnt[w & (BPB - 1)], 1);  // rank = old count
    ns++;
  }
  __syncthreads();
  // inclusive scan of lcnt -> excl (exclusive)
  __shared__ int scanv[BPB];
  if (tid < BPB) scanv[tid] = lcnt[tid];
  __syncthreads();
#pragma unroll
  for (int d = 1; d < BPB; d <<= 1) {
    int t = (tid < BPB && tid >= d) ? scanv[tid - d] : 0;
    __syncthreads();
    if (tid < BPB && tid >= d) scanv[tid] += t;
    __syncthreads();
  }
  if (tid < BPB) excl[tid] = scanv[tid] - lcnt[tid];
  if (tid < nb) {
    offs[node0 + tid] = base + (scanv[tid] - lcnt[tid]);
    dinv[node0 + tid] = rsqrtf((float)(lcnt[tid] + 1));  // +1 self-loop
  }
  __syncthreads();
  for (int j = 0; j < ns; ++j) {
    int w = stash[j];
    sbuf[excl[w & (BPB - 1)] + rank[j]] = w >> BSHIFT;
  }
  __syncthreads();
  for (int i = tid; i < size; i += 1024) csr[base + i] = sbuf[i];
}

// ---------------- pull64 (prescaled fp16, 4 edges/instr) + fused gemm2 -------
__global__ __launch_bounds__(256) void k_pull64(const __half* __restrict__ h, const int* __restrict__ offs,
                                                const int* __restrict__ csr, const float* __restrict__ dinv,
                                                const float* __restrict__ b1, const float* __restrict__ W2,
                                                float* __restrict__ h2, int n) {
  __shared__ float sa[4][65];
  __shared__ float w2s[512];
  const int tid = threadIdx.x;
  w2s[tid] = W2[tid];
  w2s[tid + 256] = W2[tid + 256];
  const int lane = tid & 63;
  const int wv = tid >> 6;
  const int node = blockIdx.x * 4 + wv;
  const int q = lane >> 4;    // edge slot 0..3
  const int f8 = lane & 15;   // 8B chunk: feats f8*4 .. +3
  const uint2* hp = (const uint2*)h;  // row = 16 uint2
  float ax = 0.f, ay = 0.f, az = 0.f, aw = 0.f;
  if (node < n) {
    const int s0 = offs[node], s1 = offs[node + 1];
    const int cnt = s1 - s0;
    auto acc1 = [&](int src) {
      uint2 vv = hp[(size_t)src * 16 + f8];
      __half2 h0 = *(__half2*)&vv.x;
      __half2 h1v = *(__half2*)&vv.y;
      float2 f0 = __half22float2(h0);
      float2 f1 = __half22float2(h1v);
      ax += f0.x; ay += f0.y; az += f1.x; aw += f1.y;
    };
    int base = 0;
    for (; base + 16 <= cnt; base += 16) {  // 16 edges: 4 per quarter, 4 chains
      int e = s0 + base + q;
      int i0 = csr[e], i1 = csr[e + 4], i2 = csr[e + 8], i3 = csr[e + 12];
      acc1(i0); acc1(i1); acc1(i2); acc1(i3);
    }
    for (; base + 4 <= cnt; base += 4) acc1(csr[s0 + base + q]);
    if (base + q < cnt) acc1(csr[s0 + base + q]);  // tail 0..3
    if (q == 0) acc1(node);                        // self-loop once
  }
  ax += __shfl_down(ax, 32); ay += __shfl_down(ay, 32);
  az += __shfl_down(az, 32); aw += __shfl_down(aw, 32);
  ax += __shfl_down(ax, 16); ay += __shfl_down(ay, 16);
  az += __shfl_down(az, 16); aw += __shfl_down(aw, 16);
  if (node < n && lane < 16) {
    float di = dinv[node];
    float4 bb = *(const float4*)(b1 + 4 * f8);
    sa[wv][4 * f8 + 0] = fmaxf(fmaf(di, ax, bb.x), 0.f);
    sa[wv][4 * f8 + 1] = fmaxf(fmaf(di, ay, bb.y), 0.f);
    sa[wv][4 * f8 + 2] = fmaxf(fmaf(di, az, bb.z), 0.f);
    sa[wv][4 * f8 + 3] = fmaxf(fmaf(di, aw, bb.w), 0.f);
  }
  __syncthreads();
  if (tid < 32) {
    int j = tid >> 3, f = tid & 7;
    int nd = blockIdx.x * 4 + j;
    if (nd < n) {
      float s = 0.f;
#pragma unroll
      for (int l = 0; l < 64; ++l) s = fmaf(sa[j][l], w2s[l * 8 + f], s);
      h2[(size_t)nd * 8 + f] = dinv[nd] * s;  // prescale for pull8
    }
  }
}

// ---------------- pull8 (prescaled, 2 chains) + fused gemm3 ----------------
__global__ __launch_bounds__(256) void k_pull8(const float* __restrict__ h, const int* __restrict__ offs,
                                               const int* __restrict__ csr, const float* __restrict__ dinv,
                                               const float* __restrict__ b2, const float* __restrict__ W3,
                                               float* __restrict__ h3, int n) {
  __shared__ float sa[4][8];
  __shared__ float w3s[32];
  const int tid = threadIdx.x;
  if (tid < 32) w3s[tid] = W3[tid];
  const int lane = tid & 63;
  const int wv = tid >> 6;
  const int node = blockIdx.x * 4 + wv;
  const int j8 = lane >> 3, f = lane & 7;
  float pa = 0.f, pb = 0.f;
  if (node < n) {
    int s0 = offs[node], s1 = offs[node + 1];
    int e0 = s0;
    for (; e0 + 16 <= s1; e0 += 16) {  // 2 independent gather chains
      int sA = csr[e0 + j8], sB = csr[e0 + 8 + j8];
      pa += h[(size_t)sA * 8 + f];
      pb += h[(size_t)sB * 8 + f];
    }
    for (; e0 < s1; e0 += 8) {
      int e = e0 + j8;
      if (e < s1) pa += h[(size_t)csr[e] * 8 + f];
    }
  }
  float pacc = pa + pb;
  pacc += __shfl_down(pacc, 32);
  pacc += __shfl_down(pacc, 16);
  pacc += __shfl_down(pacc, 8);
  if (node < n && lane < 8) {
    float v = pacc + h[(size_t)node * 8 + f];  // self-loop (prescaled)
    sa[wv][f] = fmaxf(fmaf(dinv[node], v, b2[f]), 0.f);
  }
  __syncthreads();
  if (tid < 16) {
    int j = tid >> 2, ff = tid & 3;
    int nd = blockIdx.x * 4 + j;
    if (nd < n) {
      float s = 0.f;
#pragma unroll
      for (int k = 0; k < 8; ++k) s = fmaf(sa[j][k], w3s[k * 4 + ff], s);
      h3[(size_t)nd * 4 + ff] = dinv[nd] * s;  // prescale for pull4
    }
  }
}

// ---------------- pull4 (prescaled h3 -> prescaled a3, 2 chains) -------------
__global__ __launch_bounds__(256) void k_pull4(const float* __restrict__ h, const int* __restrict__ offs,
                                               const int* __restrict__ csr, const float* __restrict__ dinv,
                                               const float* __restrict__ b3, float* __restrict__ out, int n) {
  const int tid = threadIdx.x;
  const int lane = tid & 63;
  const int node = blockIdx.x * 4 + (tid >> 6);
  if (node >= n) return;
  const int j16 = lane >> 2, f = lane & 3;
  int s0 = offs[node], s1 = offs[node + 1];
  float pa = 0.f, pb = 0.f;
  int e0 = s0;
  for (; e0 + 32 <= s1; e0 += 32) {  // 2 independent gather chains
    int sA = csr[e0 + j16], sB = csr[e0 + 16 + j16];
    pa += h[(size_t)sA * 4 + f];
    pb += h[(size_t)sB * 4 + f];
  }
  for (; e0 < s1; e0 += 16) {
    int e = e0 + j16;
    if (e < s1) pa += h[(size_t)csr[e] * 4 + f];
  }
  float pacc = pa + pb;
  pacc += __shfl_down(pacc, 32);
  pacc += __shfl_down(pacc, 16);
  pacc += __shfl_down(pacc, 8);
  pacc += __shfl_down(pacc, 4);
  if (lane < 4) {
    float di = dinv[node];
    float v = pacc + h[(size_t)node * 4 + f];  // self-loop (prescaled)
    out[(size_t)node * 4 + f] = di * fmaxf(fmaf(di, v, b3[f]), 0.f);  // prescale for pull4o
  }
}

// ---------------- final pull4 (prescaled a3, 2 chains) + fused mu/lv heads ---
__global__ __launch_bounds__(256) void k_pull4o(const float* __restrict__ a3, const int* __restrict__ offs,
                                                const int* __restrict__ csr, const float* __restrict__ dinv,
                                                const float* __restrict__ Wmu, const float* __restrict__ bmu,
                                                const float* __restrict__ Wlv, const float* __restrict__ blv,
                                                float* __restrict__ outp, int n) {
  __shared__ float sg[4][4];
  const int tid = threadIdx.x;
  const int lane = tid & 63;
  const int wv = tid >> 6;
  const int node = blockIdx.x * 4 + wv;
  const int j16 = lane >> 2, f = lane & 3;
  float pa = 0.f, pb = 0.f;
  if (node < n) {
    int s0 = offs[node], s1 = offs[node + 1];
    int e0 = s0;
    for (; e0 + 32 <= s1; e0 += 32) {
      int sA = csr[e0 + j16], sB = csr[e0 + 16 + j16];
      pa += a3[(size_t)sA * 4 + f];
      pb += a3[(size_t)sB * 4 + f];
    }
    for (; e0 < s1; e0 += 16) {
      int e = e0 + j16;
      if (e < s1) pa += a3[(size_t)csr[e] * 4 + f];
    }
  }
  float pacc = pa + pb;
  pacc += __shfl_down(pacc, 32);
  pacc += __shfl_down(pacc, 16);
  pacc += __shfl_down(pacc, 8);
  pacc += __shfl_down(pacc, 4);
  if (node < n && lane < 4) {
    float v = pacc + a3[(size_t)node * 4 + f];  // self-loop (prescaled)
    sg[wv][f] = dinv[node] * v;
  }
  __syncthreads();
  if (tid < 16) {
    int j = tid >> 2, c = tid & 3;  // c: 0=mu0 1=mu1 2=lv0 3=lv1
    int nd = blockIdx.x * 4 + j;
    if (nd < n) {
      const float* Wp = (c < 2) ? Wmu : Wlv;
      const float* bp = (c < 2) ? bmu : blv;
      int cc = c & 1;
      float s = bp[cc];
#pragma unroll
      for (int k = 0; k < 4; ++k) s = fmaf(sg[j][k], Wp[k * 2 + cc], s);
      size_t base = (c < 2) ? 0 : (size_t)2 * n;
      outp[base + (size_t)nd * 2 + cc] = s;
    }
  }
}

extern "C" void kernel_launch(void* const* d_in, const int* in_sizes, int n_in,
                              void* d_out, int out_size, void* d_ws, size_t ws_size,
                              hipStream_t stream) {
  const float* x = (const float*)d_in[0];
  const int* ei = (const int*)d_in[1];
  const float* W1 = (const float*)d_in[2];
  const float* b1 = (const float*)d_in[3];
  const float* W2 = (const float*)d_in[4];
  const float* b2 = (const float*)d_in[5];
  const float* W3 = (const float*)d_in[6];
  const float* b3 = (const float*)d_in[7];
  const float* Wmu = (const float*)d_in[8];
  const float* bmu = (const float*)d_in[9];
  const float* Wlv = (const float*)d_in[10];
  const float* blv = (const float*)d_in[11];
  float* out = (float*)d_out;

  const int N = in_sizes[0] / 512;
  const int E = in_sizes[1] / 2;
  const int* esrc = ei;
  const int* edst = ei + E;
  const int NB = (N + BPB - 1) >> BSHIFT;  // 782

  char* w = (char*)d_ws;
  size_t p = 0;
  auto alloc = [&](size_t bytes) -> void* {
    void* r = w + p;
    p = (p + bytes + 255) & ~(size_t)255;
    return r;
  };
  int* bcnt = (int*)alloc((size_t)NB * 16 * 4);  // 64B-padded counters
  int* bbase = (int*)alloc((size_t)NB * 4);
  int* offs = (int*)alloc((size_t)(N + 1) * 4);
  float* dinv = (float*)alloc((size_t)N * 4);
  int* csr = (int*)alloc((size_t)E * 4);
  int* pairs = (int*)alloc((size_t)NB * CAP * 4);
  __half* h1 = (__half*)alloc((size_t)N * 64 * 2);
  float* h2 = (float*)alloc((size_t)N * 8 * 4);
  float* h3 = (float*)alloc((size_t)N * 4 * 4);
  float* a3 = (float*)alloc((size_t)N * 4 * 4);
  _Float16* wf = (_Float16*)alloc((size_t)512 * 64 * 2);  // W1 fp16 frag layout

  hipMemsetAsync(bcnt, 0, (size_t)NB * 16 * 4, stream);

  k_wprep<<<16, 256, 0, stream>>>(W1, wf);
  k_part<<<256, 1024, 0, stream>>>(esrc, edst, bcnt, pairs, E, NB, 256);
  k_bscan<<<1, 1024, 0, stream>>>(bcnt, bbase, offs, NB, N, E);
  k_p2<<<NB, 1024, 0, stream>>>(pairs, bcnt, bbase, offs, dinv, csr, N);
  k_gemm1m<<<(N + 127) / 128, 256, 0, stream>>>(x, wf, dinv, h1, N);  // after p2: dinv prescale

  k_pull64<<<(N + 3) / 4, 256, 0, stream>>>(h1, offs, csr, dinv, b1, W2, h2, N);
  k_pull8<<<(N + 3) / 4, 256, 0, stream>>>(h2, offs, csr, dinv, b2, W3, h3, N);
  k_pull4<<<(N + 3) / 4, 256, 0, stream>>>(h3, offs, csr, dinv, b3, a3, N);
  k_pull4o<<<(N + 3) / 4, 256, 0, stream>>>(a3, offs, csr, dinv, Wmu, bmu, Wlv, blv, out, N);
}